// Round 1
// baseline (2334.050 us; speedup 1.0000x reference)
//
#include <hip/hip_runtime.h>
#include <hip/hip_bf16.h>
#include <cstddef>

// Problem constants (match reference)
#define Bz 128
#define Pz 196
#define Fz 2048
#define Ez 512
#define Hz 512
#define Vz 10000
#define Tz 32
#define TM (Tz - 1)          // 31 time steps
#define Mrows (Bz * TM)      // 3968
#define G4 (4 * Hz)          // 2048 gate width

// ---------------------------------------------------------------------------
// gather indices: gidx[m] = captions[b*32 + t],  m = b*31 + t
__global__ __launch_bounds__(256) void build_gidx(const int* __restrict__ cap,
                                                  int* __restrict__ gidx) {
    int m = blockIdx.x * 256 + threadIdx.x;
    if (m < Mrows) {
        int b = m / TM;
        int t = m - b * TM;
        gidx[m] = cap[b * Tz + t];
    }
}

// ---------------------------------------------------------------------------
// mean over P: features [B][P][F] -> mean [B][F], float4 vectorized
__global__ __launch_bounds__(256) void meanpool(const float* __restrict__ feat,
                                                float* __restrict__ mean) {
    int idx = blockIdx.x * 256 + threadIdx.x;     // 0 .. B*F/4-1
    int b = idx >> 9;                             // F/4 = 512 float4 per row
    int q = idx & 511;
    const float4* base = reinterpret_cast<const float4*>(feat) +
                         (size_t)b * Pz * (Fz / 4) + q;
    float4 acc = {0.f, 0.f, 0.f, 0.f};
    for (int p = 0; p < Pz; ++p) {
        float4 v = base[(size_t)p * (Fz / 4)];
        acc.x += v.x; acc.y += v.y; acc.z += v.z; acc.w += v.w;
    }
    const float s = 1.0f / (float)Pz;
    acc.x *= s; acc.y *= s; acc.z *= s; acc.w *= s;
    reinterpret_cast<float4*>(mean)[idx] = acc;
}

// ---------------------------------------------------------------------------
// transpose W_hh [2048][512] -> W_hhT [512][2048], 32x32 LDS tiles
__global__ __launch_bounds__(256) void transpose_whh(const float* __restrict__ W,
                                                     float* __restrict__ WT) {
    __shared__ float tile[32][33];
    int kx = blockIdx.x;           // 0..15  (512/32)
    int gy = blockIdx.y;           // 0..63  (2048/32)
    int tx = threadIdx.x & 31;
    int ty = threadIdx.x >> 5;     // 0..7
#pragma unroll
    for (int i = 0; i < 4; ++i) {
        int r = ty + i * 8;
        tile[r][tx] = W[(size_t)(gy * 32 + r) * Ez + kx * 32 + tx];
    }
    __syncthreads();
#pragma unroll
    for (int i = 0; i < 4; ++i) {
        int r = ty + i * 8;
        WT[(size_t)(kx * 32 + r) * G4 + gy * 32 + tx] = tile[tx][r];
    }
}

// ---------------------------------------------------------------------------
// fp32 tiled GEMM:  C[m][n] = dot(A_row(m), B[n][:]) + bias1[n] + bias2[n]
//   A_row(m) = A[(gidx?gidx[m]:m) * lda + :]   (row-major, K contiguous)
//   B is [N][K] row-major. BM=BN=64, BK=32, 256 threads, 4x4 micro-tile.
__global__ __launch_bounds__(256) void gemm_rr(
    const float* __restrict__ A, int lda,
    const int* __restrict__ gidx,
    const float* __restrict__ B, int ldb,
    const float* __restrict__ bias1, const float* __restrict__ bias2,
    float* __restrict__ C, int ldc,
    int M, int N, int K)
{
    __shared__ float As[64][33];
    __shared__ float Bs[64][33];
    const int m0 = blockIdx.y * 64;
    const int n0 = blockIdx.x * 64;
    const int tid = threadIdx.x;
    const int tx = tid & 15, ty = tid >> 4;   // 16x16 thread grid
    float acc[4][4] = {};

    for (int k0 = 0; k0 < K; k0 += 32) {
#pragma unroll
        for (int i = 0; i < 2; ++i) {
            int e  = tid + i * 256;        // float4 slot 0..511
            int r  = e >> 3;               // 8 float4 per 32-wide row
            int cc = (e & 7) << 2;
            int m = m0 + r;
            float4 va = {0.f, 0.f, 0.f, 0.f};
            if (m < M) {
                int row = gidx ? gidx[m] : m;
                va = *reinterpret_cast<const float4*>(A + (size_t)row * lda + k0 + cc);
            }
            As[r][cc + 0] = va.x; As[r][cc + 1] = va.y;
            As[r][cc + 2] = va.z; As[r][cc + 3] = va.w;
            int n = n0 + r;
            float4 vb = {0.f, 0.f, 0.f, 0.f};
            if (n < N)
                vb = *reinterpret_cast<const float4*>(B + (size_t)n * ldb + k0 + cc);
            Bs[r][cc + 0] = vb.x; Bs[r][cc + 1] = vb.y;
            Bs[r][cc + 2] = vb.z; Bs[r][cc + 3] = vb.w;
        }
        __syncthreads();
#pragma unroll
        for (int kk = 0; kk < 32; ++kk) {
            float a[4], bb[4];
#pragma unroll
            for (int i = 0; i < 4; ++i) a[i] = As[ty * 4 + i][kk];
#pragma unroll
            for (int j = 0; j < 4; ++j) bb[j] = Bs[tx * 4 + j][kk];
#pragma unroll
            for (int i = 0; i < 4; ++i)
#pragma unroll
                for (int j = 0; j < 4; ++j)
                    acc[i][j] += a[i] * bb[j];
        }
        __syncthreads();
    }

#pragma unroll
    for (int i = 0; i < 4; ++i) {
        int m = m0 + ty * 4 + i;
        if (m >= M) continue;
#pragma unroll
        for (int j = 0; j < 4; ++j) {
            int n = n0 + tx * 4 + j;
            if (n >= N) continue;
            float v = acc[i][j];
            if (bias1) v += bias1[n];
            if (bias2) v += bias2[n];
            C[(size_t)m * ldc + n] = v;
        }
    }
}

// ---------------------------------------------------------------------------
// One LSTM step. gates[b][g] = xg[b*31+t][g] + dot(h_prev[b], W_hhT[:, g])
// Each thread owns one (b, h): computes i,f,g~,o dots, then elementwise.
// h_prev read from h0 (t==0) or hs[b][t-1]; h_new written to hs[b][t].
// c updated in place (one thread per element -> no race).
__global__ __launch_bounds__(128) void lstm_step(
    const float* __restrict__ xg, const float* __restrict__ WhhT,
    const float* __restrict__ h0, float* __restrict__ c,
    float* __restrict__ hs, int t)
{
    const int b = blockIdx.x >> 2;
    const int chunk = blockIdx.x & 3;
    __shared__ float hrow[Hz];
    const float* hin = (t == 0) ? (h0 + (size_t)b * Hz)
                                : (hs + ((size_t)b * TM + (t - 1)) * Hz);
    for (int j = threadIdx.x; j < Hz; j += 128) hrow[j] = hin[j];
    __syncthreads();

    const int hidx = chunk * 128 + threadIdx.x;
    const float* xr = xg + ((size_t)b * TM + t) * G4;
    float ai = xr[hidx];
    float af = xr[hidx + Hz];
    float ag = xr[hidx + 2 * Hz];
    float ao = xr[hidx + 3 * Hz];

#pragma unroll 8
    for (int k = 0; k < Hz; ++k) {
        float hv = hrow[k];
        const float* wr = WhhT + (size_t)k * G4 + hidx;
        ai += hv * wr[0];
        af += hv * wr[Hz];
        ag += hv * wr[2 * Hz];
        ao += hv * wr[3 * Hz];
    }

    float ig = 1.0f / (1.0f + expf(-ai));
    float fg = 1.0f / (1.0f + expf(-af));
    float gg = tanhf(ag);
    float og = 1.0f / (1.0f + expf(-ao));
    size_t cix = (size_t)b * Hz + hidx;
    float cn = fg * c[cix] + ig * gg;
    float hn = og * tanhf(cn);
    c[cix] = cn;
    hs[((size_t)b * TM + t) * Hz + hidx] = hn;
}

// ---------------------------------------------------------------------------
extern "C" void kernel_launch(void* const* d_in, const int* in_sizes, int n_in,
                              void* d_out, int out_size, void* d_ws, size_t ws_size,
                              hipStream_t stream) {
    const float* features = (const float*)d_in[0];
    const int*   captions = (const int*)d_in[1];
    const float* emb_W    = (const float*)d_in[2];
    const float* W_ih     = (const float*)d_in[3];
    const float* W_hh     = (const float*)d_in[4];
    const float* b_ih     = (const float*)d_in[5];
    const float* b_hh     = (const float*)d_in[6];
    const float* Wh       = (const float*)d_in[7];
    const float* bh       = (const float*)d_in[8];
    const float* Wc       = (const float*)d_in[9];
    const float* bc       = (const float*)d_in[10];
    const float* fc_W     = (const float*)d_in[11];
    const float* fc_b     = (const float*)d_in[12];
    float* out = (float*)d_out;

    // workspace carve-up (floats)
    float* w      = (float*)d_ws;
    float* mean   = w;                      // 128*2048        = 262144
    float* h0     = mean + Bz * Fz;         // 128*512         = 65536
    float* cbuf   = h0 + Bz * Hz;           // 128*512         = 65536
    float* WhhT   = cbuf + Bz * Hz;         // 512*2048        = 1048576
    float* xg     = WhhT + Ez * G4;         // 3968*2048       = 8126464
    float* hs     = xg + (size_t)Mrows * G4;// 3968*512        = 2031616
    int*   gidx   = (int*)(hs + (size_t)Mrows * Hz);  // 3968 ints

    // 1. gather indices
    build_gidx<<<(Mrows + 255) / 256, 256, 0, stream>>>(captions, gidx);

    // 2. mean pool
    meanpool<<<(Bz * Fz / 4) / 256, 256, 0, stream>>>(features, mean);

    // 3. transpose W_hh
    transpose_whh<<<dim3(Ez / 32, G4 / 32), 256, 0, stream>>>(W_hh, WhhT);

    // 4. h0 = mean @ Wh^T + bh ; c0 = mean @ Wc^T + bc
    gemm_rr<<<dim3(Hz / 64, Bz / 64), 256, 0, stream>>>(
        mean, Fz, nullptr, Wh, Fz, bh, nullptr, h0, Hz, Bz, Hz, Fz);
    gemm_rr<<<dim3(Hz / 64, Bz / 64), 256, 0, stream>>>(
        mean, Fz, nullptr, Wc, Fz, bc, nullptr, cbuf, Hz, Bz, Hz, Fz);

    // 5. x-side gate preactivations: xg[b*31+t][g] = emb @ W_ih^T + b_ih + b_hh
    gemm_rr<<<dim3(G4 / 64, Mrows / 64), 256, 0, stream>>>(
        emb_W, Ez, gidx, W_ih, Ez, b_ih, b_hh, xg, G4, Mrows, G4, Ez);

    // 6. recurrence
    for (int t = 0; t < TM; ++t) {
        lstm_step<<<Bz * 4, 128, 0, stream>>>(xg, WhhT, h0, cbuf, hs, t);
    }

    // 7. output projection: out[b][t][v] = hs[b][t] . fc_W[v] + fc_b[v]
    gemm_rr<<<dim3((Vz + 63) / 64, Mrows / 64), 256, 0, stream>>>(
        hs, Hz, nullptr, fc_W, Hz, fc_b, nullptr, out, Vz, Mrows, Vz, Hz);
}

// Round 2
// 1583.575 us; speedup vs baseline: 1.4739x; 1.4739x over previous
//
#include <hip/hip_runtime.h>
#include <hip/hip_bf16.h>
#include <cstddef>

// Problem constants (match reference)
#define Bz 128
#define Pz 196
#define Fz 2048
#define Ez 512
#define Hz 512
#define Vz 10000
#define Tz 32
#define TM (Tz - 1)          // 31 time steps
#define Mrows (Bz * TM)      // 3968
#define G4 (4 * Hz)          // 2048 gate width
#define NPAD 10112           // 79 * 128, padded vocab for MFMA tiles

typedef __attribute__((ext_vector_type(8))) short bf16x8;
typedef __attribute__((ext_vector_type(4))) float f32x4;

__device__ __forceinline__ void gload_lds16(const void* g, void* l) {
    __builtin_amdgcn_global_load_lds(
        (const __attribute__((address_space(1))) unsigned int*)g,
        (__attribute__((address_space(3))) unsigned int*)l, 16, 0, 0);
}

// ---------------------------------------------------------------------------
// gather indices: gidx[m] = captions[b*32 + t],  m = b*31 + t
__global__ __launch_bounds__(256) void build_gidx(const int* __restrict__ cap,
                                                  int* __restrict__ gidx) {
    int m = blockIdx.x * 256 + threadIdx.x;
    if (m < Mrows) {
        int b = m / TM;
        int t = m - b * TM;
        gidx[m] = cap[b * Tz + t];
    }
}

// ---------------------------------------------------------------------------
// mean over P: features [B][P][F] -> mean [B][F], float4 vectorized
__global__ __launch_bounds__(256) void meanpool(const float* __restrict__ feat,
                                                float* __restrict__ mean) {
    int idx = blockIdx.x * 256 + threadIdx.x;     // 0 .. B*F/4-1
    int b = idx >> 9;                             // F/4 = 512 float4 per row
    int q = idx & 511;
    const float4* base = reinterpret_cast<const float4*>(feat) +
                         (size_t)b * Pz * (Fz / 4) + q;
    float4 acc = {0.f, 0.f, 0.f, 0.f};
    for (int p = 0; p < Pz; ++p) {
        float4 v = base[(size_t)p * (Fz / 4)];
        acc.x += v.x; acc.y += v.y; acc.z += v.z; acc.w += v.w;
    }
    const float s = 1.0f / (float)Pz;
    acc.x *= s; acc.y *= s; acc.z *= s; acc.w *= s;
    reinterpret_cast<float4*>(mean)[idx] = acc;
}

// ---------------------------------------------------------------------------
// transpose W_hh [2048][512] -> W_hhT [512][2048], 32x32 LDS tiles
__global__ __launch_bounds__(256) void transpose_whh(const float* __restrict__ W,
                                                     float* __restrict__ WT) {
    __shared__ float tile[32][33];
    int kx = blockIdx.x;           // 0..15  (512/32)
    int gy = blockIdx.y;           // 0..63  (2048/32)
    int tx = threadIdx.x & 31;
    int ty = threadIdx.x >> 5;     // 0..7
#pragma unroll
    for (int i = 0; i < 4; ++i) {
        int r = ty + i * 8;
        tile[r][tx] = W[(size_t)(gy * 32 + r) * Ez + kx * 32 + tx];
    }
    __syncthreads();
#pragma unroll
    for (int i = 0; i < 4; ++i) {
        int r = ty + i * 8;
        WT[(size_t)(kx * 32 + r) * G4 + gy * 32 + tx] = tile[tx][r];
    }
}

// ---------------------------------------------------------------------------
// f32 -> bf16 convert with zero padding, 4 elems per thread.
// n4src/n4dst are counts of float4 groups (src count must be multiple of 4).
__global__ __launch_bounds__(256) void cvt_bf16_pad4(const float* __restrict__ s,
                                                     ushort* __restrict__ d,
                                                     int n4src, int n4dst) {
    int i = blockIdx.x * 256 + threadIdx.x;
    if (i >= n4dst) return;
    ushort4 o;
    if (i < n4src) {
        float4 v = reinterpret_cast<const float4*>(s)[i];
        __hip_bfloat16 bx = __float2bfloat16(v.x);
        __hip_bfloat16 by = __float2bfloat16(v.y);
        __hip_bfloat16 bz = __float2bfloat16(v.z);
        __hip_bfloat16 bw = __float2bfloat16(v.w);
        o.x = *reinterpret_cast<ushort*>(&bx);
        o.y = *reinterpret_cast<ushort*>(&by);
        o.z = *reinterpret_cast<ushort*>(&bz);
        o.w = *reinterpret_cast<ushort*>(&bw);
    } else {
        o.x = o.y = o.z = o.w = 0;   // bf16 zero
    }
    reinterpret_cast<ushort4*>(d)[i] = o;
}

// ---------------------------------------------------------------------------
// bf16 MFMA GEMM (m97 structure): C[m][n] = dot(A[m], B[n]) + bias[n]
// A [M][K] bf16 row-major (K-contig), B [Npad][K] bf16 row-major.
// 128x128 tile, BK=32, 256 threads = 4 waves in 2x2, 4x4 16x16x32 frags/wave.
// M, K multiples of 128/32; N bound enforced on store only (B zero-padded).
__global__ __launch_bounds__(256) void gemm_mfma(
    const __hip_bfloat16* __restrict__ A,
    const __hip_bfloat16* __restrict__ B,
    const float* __restrict__ bias,
    float* __restrict__ C,
    int M, int N, int K)
{
    __shared__ short Al[128 * 32];
    __shared__ short Bl[128 * 32];
    const int tid  = threadIdx.x;
    const int w    = tid >> 6;
    const int lane = tid & 63;
    const int m0 = blockIdx.y * 128;
    const int n0 = blockIdx.x * 128;
    const int wr = w >> 1, wc = w & 1;

    f32x4 acc[4][4] = {};

    // staging: each wave fills 32 rows (2 instrs x 16 rows); 4 lanes per 64B row
    const int srow = w * 32 + (lane >> 2);
    const int scol = (lane & 3) * 16;              // byte offset in 64B row
    const char* Ag = (const char*)(A + (size_t)(m0 + srow) * K) + scol;
    const char* Bg = (const char*)(B + (size_t)(n0 + srow) * K) + scol;
    const size_t rstep = (size_t)16 * K * 2;       // 16 rows in bytes
    short* Alb = Al + (w * 32) * 32;               // LDS base (wave-uniform)
    short* Blb = Bl + (w * 32) * 32;

    const int ko = (lane >> 4) * 8;                // k-offset within fragment
    const int fr = lane & 15;                      // fragment row/col

    for (int k0 = 0; k0 < K; k0 += 32) {
        const size_t kb = (size_t)k0 * 2;
        gload_lds16(Ag + kb,         Alb);
        gload_lds16(Ag + kb + rstep, Alb + 16 * 32);
        gload_lds16(Bg + kb,         Blb);
        gload_lds16(Bg + kb + rstep, Blb + 16 * 32);
        __syncthreads();

        bf16x8 af[4], bf[4];
#pragma unroll
        for (int i = 0; i < 4; ++i)
            af[i] = *reinterpret_cast<const bf16x8*>(&Al[(wr * 64 + i * 16 + fr) * 32 + ko]);
#pragma unroll
        for (int j = 0; j < 4; ++j)
            bf[j] = *reinterpret_cast<const bf16x8*>(&Bl[(wc * 64 + j * 16 + fr) * 32 + ko]);
#pragma unroll
        for (int i = 0; i < 4; ++i)
#pragma unroll
            for (int j = 0; j < 4; ++j)
                acc[i][j] = __builtin_amdgcn_mfma_f32_16x16x32_bf16(
                    af[i], bf[j], acc[i][j], 0, 0, 0);
        __syncthreads();
    }

    // epilogue: C/D layout col = lane&15, row = (lane>>4)*4 + reg
    const int r0 = (lane >> 4) * 4;
#pragma unroll
    for (int i = 0; i < 4; ++i) {
        int row = m0 + wr * 64 + i * 16 + r0;
#pragma unroll
        for (int j = 0; j < 4; ++j) {
            int col = n0 + wc * 64 + j * 16 + fr;
            if (col < N) {
                float bb = bias ? bias[col] : 0.f;
#pragma unroll
                for (int r = 0; r < 4; ++r)
                    C[(size_t)(row + r) * N + col] = acc[i][j][r] + bb;
            }
        }
    }
}

// ---------------------------------------------------------------------------
// fp32 tiled GEMM (kept for init/xg):  C = A(gidx) @ B^T + bias1 + bias2
__global__ __launch_bounds__(256) void gemm_rr(
    const float* __restrict__ A, int lda,
    const int* __restrict__ gidx,
    const float* __restrict__ B, int ldb,
    const float* __restrict__ bias1, const float* __restrict__ bias2,
    float* __restrict__ C, int ldc,
    int M, int N, int K)
{
    __shared__ float As[64][33];
    __shared__ float Bs[64][33];
    const int m0 = blockIdx.y * 64;
    const int n0 = blockIdx.x * 64;
    const int tid = threadIdx.x;
    const int tx = tid & 15, ty = tid >> 4;   // 16x16 thread grid
    float acc[4][4] = {};

    for (int k0 = 0; k0 < K; k0 += 32) {
#pragma unroll
        for (int i = 0; i < 2; ++i) {
            int e  = tid + i * 256;        // float4 slot 0..511
            int r  = e >> 3;               // 8 float4 per 32-wide row
            int cc = (e & 7) << 2;
            int m = m0 + r;
            float4 va = {0.f, 0.f, 0.f, 0.f};
            if (m < M) {
                int row = gidx ? gidx[m] : m;
                va = *reinterpret_cast<const float4*>(A + (size_t)row * lda + k0 + cc);
            }
            As[r][cc + 0] = va.x; As[r][cc + 1] = va.y;
            As[r][cc + 2] = va.z; As[r][cc + 3] = va.w;
            int n = n0 + r;
            float4 vb = {0.f, 0.f, 0.f, 0.f};
            if (n < N)
                vb = *reinterpret_cast<const float4*>(B + (size_t)n * ldb + k0 + cc);
            Bs[r][cc + 0] = vb.x; Bs[r][cc + 1] = vb.y;
            Bs[r][cc + 2] = vb.z; Bs[r][cc + 3] = vb.w;
        }
        __syncthreads();
#pragma unroll
        for (int kk = 0; kk < 32; ++kk) {
            float a[4], bb[4];
#pragma unroll
            for (int i = 0; i < 4; ++i) a[i] = As[ty * 4 + i][kk];
#pragma unroll
            for (int j = 0; j < 4; ++j) bb[j] = Bs[tx * 4 + j][kk];
#pragma unroll
            for (int i = 0; i < 4; ++i)
#pragma unroll
                for (int j = 0; j < 4; ++j)
                    acc[i][j] += a[i] * bb[j];
        }
        __syncthreads();
    }

#pragma unroll
    for (int i = 0; i < 4; ++i) {
        int m = m0 + ty * 4 + i;
        if (m >= M) continue;
#pragma unroll
        for (int j = 0; j < 4; ++j) {
            int n = n0 + tx * 4 + j;
            if (n >= N) continue;
            float v = acc[i][j];
            if (bias1) v += bias1[n];
            if (bias2) v += bias2[n];
            C[(size_t)m * ldc + n] = v;
        }
    }
}

// ---------------------------------------------------------------------------
// One LSTM step (unchanged this round; L2-bound, next round's target)
__global__ __launch_bounds__(128) void lstm_step(
    const float* __restrict__ xg, const float* __restrict__ WhhT,
    const float* __restrict__ h0, float* __restrict__ c,
    float* __restrict__ hs, int t)
{
    const int b = blockIdx.x >> 2;
    const int chunk = blockIdx.x & 3;
    __shared__ float hrow[Hz];
    const float* hin = (t == 0) ? (h0 + (size_t)b * Hz)
                                : (hs + ((size_t)b * TM + (t - 1)) * Hz);
    for (int j = threadIdx.x; j < Hz; j += 128) hrow[j] = hin[j];
    __syncthreads();

    const int hidx = chunk * 128 + threadIdx.x;
    const float* xr = xg + ((size_t)b * TM + t) * G4;
    float ai = xr[hidx];
    float af = xr[hidx + Hz];
    float ag = xr[hidx + 2 * Hz];
    float ao = xr[hidx + 3 * Hz];

#pragma unroll 8
    for (int k = 0; k < Hz; ++k) {
        float hv = hrow[k];
        const float* wr = WhhT + (size_t)k * G4 + hidx;
        ai += hv * wr[0];
        af += hv * wr[Hz];
        ag += hv * wr[2 * Hz];
        ao += hv * wr[3 * Hz];
    }

    float ig = 1.0f / (1.0f + expf(-ai));
    float fg = 1.0f / (1.0f + expf(-af));
    float gg = tanhf(ag);
    float og = 1.0f / (1.0f + expf(-ao));
    size_t cix = (size_t)b * Hz + hidx;
    float cn = fg * c[cix] + ig * gg;
    float hn = og * tanhf(cn);
    c[cix] = cn;
    hs[((size_t)b * TM + t) * Hz + hidx] = hn;
}

// ---------------------------------------------------------------------------
extern "C" void kernel_launch(void* const* d_in, const int* in_sizes, int n_in,
                              void* d_out, int out_size, void* d_ws, size_t ws_size,
                              hipStream_t stream) {
    const float* features = (const float*)d_in[0];
    const int*   captions = (const int*)d_in[1];
    const float* emb_W    = (const float*)d_in[2];
    const float* W_ih     = (const float*)d_in[3];
    const float* W_hh     = (const float*)d_in[4];
    const float* b_ih     = (const float*)d_in[5];
    const float* b_hh     = (const float*)d_in[6];
    const float* Wh       = (const float*)d_in[7];
    const float* bh       = (const float*)d_in[8];
    const float* Wc       = (const float*)d_in[9];
    const float* bc       = (const float*)d_in[10];
    const float* fc_W     = (const float*)d_in[11];
    const float* fc_b     = (const float*)d_in[12];
    float* out = (float*)d_out;

    // workspace carve-up
    float* w      = (float*)d_ws;
    float* mean   = w;                       // 128*2048   = 262144
    float* h0     = mean + Bz * Fz;          // 128*512    = 65536
    float* cbuf   = h0 + Bz * Hz;            // 128*512    = 65536
    float* WhhT   = cbuf + Bz * Hz;          // 512*2048   = 1048576
    float* xg     = WhhT + Ez * G4;          // 3968*2048  = 8126464
    float* hs     = xg + (size_t)Mrows * G4; // 3968*512   = 2031616
    int*   gidx   = (int*)(hs + (size_t)Mrows * Hz);      // 3968 ints
    __hip_bfloat16* hs_b  = (__hip_bfloat16*)(gidx + Mrows);     // 2031616 bf16
    __hip_bfloat16* fcW_b = hs_b + (size_t)Mrows * Hz;           // 10112*512 bf16

    // 1. gather indices
    build_gidx<<<(Mrows + 255) / 256, 256, 0, stream>>>(captions, gidx);

    // 2. mean pool
    meanpool<<<(Bz * Fz / 4) / 256, 256, 0, stream>>>(features, mean);

    // 3. transpose W_hh
    transpose_whh<<<dim3(Ez / 32, G4 / 32), 256, 0, stream>>>(W_hh, WhhT);

    // 3b. fc_W -> bf16, zero-padded to NPAD rows (independent; done early)
    {
        int n4src = Vz * Hz / 4;             // 1,280,000
        int n4dst = NPAD * Hz / 4;           // 1,294,336
        cvt_bf16_pad4<<<(n4dst + 255) / 256, 256, 0, stream>>>(
            fc_W, (ushort*)fcW_b, n4src, n4dst);
    }

    // 4. h0 = mean @ Wh^T + bh ; c0 = mean @ Wc^T + bc
    gemm_rr<<<dim3(Hz / 64, Bz / 64), 256, 0, stream>>>(
        mean, Fz, nullptr, Wh, Fz, bh, nullptr, h0, Hz, Bz, Hz, Fz);
    gemm_rr<<<dim3(Hz / 64, Bz / 64), 256, 0, stream>>>(
        mean, Fz, nullptr, Wc, Fz, bc, nullptr, cbuf, Hz, Bz, Hz, Fz);

    // 5. x-side gate preactivations
    gemm_rr<<<dim3(G4 / 64, Mrows / 64), 256, 0, stream>>>(
        emb_W, Ez, gidx, W_ih, Ez, b_ih, b_hh, xg, G4, Mrows, G4, Ez);

    // 6. recurrence
    for (int t = 0; t < TM; ++t) {
        lstm_step<<<Bz * 4, 128, 0, stream>>>(xg, WhhT, h0, cbuf, hs, t);
    }

    // 6b. hs -> bf16
    {
        int n4 = Mrows * Hz / 4;             // 507,904
        cvt_bf16_pad4<<<(n4 + 255) / 256, 256, 0, stream>>>(
            hs, (ushort*)hs_b, n4, n4);
    }

    // 7. output projection via bf16 MFMA: out = hs_b @ fcW_b^T + fc_b
    gemm_mfma<<<dim3(NPAD / 128, Mrows / 128), 256, 0, stream>>>(
        hs_b, fcW_b, fc_b, out, Mrows, Vz, Hz);
}

// Round 3
// 1184.931 us; speedup vs baseline: 1.9698x; 1.3364x over previous
//
#include <hip/hip_runtime.h>
#include <hip/hip_bf16.h>
#include <cstddef>

// Problem constants
#define Bz 128
#define Pz 196
#define Fz 2048
#define Ez 512
#define Hz 512
#define Vz 10000
#define Tz 32
#define TM 31                 // time steps
#define Mrows (Bz * TM)       // 3968
#define G4 (4 * Hz)           // 2048 gate width
#define NPAD 10112            // 79*128 padded vocab

typedef __attribute__((ext_vector_type(8))) short bf16x8;
typedef __attribute__((ext_vector_type(4))) float f32x4;

__device__ __forceinline__ void gload_lds16(const void* g, void* l) {
    __builtin_amdgcn_global_load_lds(
        (const __attribute__((address_space(1))) unsigned int*)g,
        (__attribute__((address_space(3))) unsigned int*)l, 16, 0, 0);
}
__device__ __forceinline__ ushort f2b(float x) {
    __hip_bfloat16 b = __float2bfloat16(x);
    return *reinterpret_cast<ushort*>(&b);
}
__device__ __forceinline__ float b2f(ushort u) {
    __hip_bfloat16 b = *reinterpret_cast<__hip_bfloat16*>(&u);
    return __bfloat162float(b);
}

// ---------------------------------------------------------------------------
__global__ __launch_bounds__(256) void build_gidx(const int* __restrict__ cap,
                                                  int* __restrict__ gidx) {
    int m = blockIdx.x * 256 + threadIdx.x;
    if (m < Mrows) {
        int b = m / TM;
        int t = m - b * TM;
        gidx[m] = cap[b * Tz + t];
    }
}

// ---------------------------------------------------------------------------
__global__ __launch_bounds__(256) void meanpool(const float* __restrict__ feat,
                                                float* __restrict__ mean) {
    int idx = blockIdx.x * 256 + threadIdx.x;
    int b = idx >> 9;
    int q = idx & 511;
    const float4* base = reinterpret_cast<const float4*>(feat) +
                         (size_t)b * Pz * (Fz / 4) + q;
    float4 acc = {0.f, 0.f, 0.f, 0.f};
    for (int p = 0; p < Pz; ++p) {
        float4 v = base[(size_t)p * (Fz / 4)];
        acc.x += v.x; acc.y += v.y; acc.z += v.z; acc.w += v.w;
    }
    const float s = 1.0f / (float)Pz;
    acc.x *= s; acc.y *= s; acc.z *= s; acc.w *= s;
    reinterpret_cast<float4*>(mean)[idx] = acc;
}

// ---------------------------------------------------------------------------
// gather caption embeddings + convert to bf16: embg[m][k] = bf16(emb[gidx[m]][k])
__global__ __launch_bounds__(256) void gather_cvt_emb(const float* __restrict__ emb,
                                                      const int* __restrict__ gidx,
                                                      ushort* __restrict__ out) {
    int idx = blockIdx.x * 256 + threadIdx.x;        // Mrows * 128
    if (idx >= Mrows * (Ez / 4)) return;
    int m = idx >> 7, kq = idx & 127;
    float4 v = reinterpret_cast<const float4*>(emb + (size_t)gidx[m] * Ez)[kq];
    ushort4 o = {f2b(v.x), f2b(v.y), f2b(v.z), f2b(v.w)};
    reinterpret_cast<ushort4*>(out + (size_t)m * Ez)[kq] = o;
}

// ---------------------------------------------------------------------------
// permute W_ih rows g*512+j -> 4j+g, convert bf16; also bP[4j+g]=b_ih+b_hh
__global__ __launch_bounds__(256) void permute_wih(const float* __restrict__ W,
                                                   const float* __restrict__ b1,
                                                   const float* __restrict__ b2,
                                                   ushort* __restrict__ WP,
                                                   float* __restrict__ bP) {
    int idx = blockIdx.x * 256 + threadIdx.x;        // 2048*128
    int o = idx >> 7, kq = idx & 127;
    int j = o >> 2, g = o & 3;
    int in = g * Hz + j;
    float4 v = reinterpret_cast<const float4*>(W + (size_t)in * Ez)[kq];
    ushort4 u = {f2b(v.x), f2b(v.y), f2b(v.z), f2b(v.w)};
    reinterpret_cast<ushort4*>(WP + (size_t)o * Ez)[kq] = u;
    if (kq == 0) bP[o] = b1[in] + b2[in];
}

// ---------------------------------------------------------------------------
// permute W_hh rows g*512+j -> 4j+g, split into bf16 hi + lo parts
__global__ __launch_bounds__(256) void permute_whh_split(const float* __restrict__ W,
                                                         ushort* __restrict__ Whi,
                                                         ushort* __restrict__ Wlo) {
    int idx = blockIdx.x * 256 + threadIdx.x;        // 2048*128
    int o = idx >> 7, kq = idx & 127;
    int j = o >> 2, g = o & 3;
    int in = g * Hz + j;
    float4 v = reinterpret_cast<const float4*>(W + (size_t)in * Hz)[kq];
    ushort4 h, l;
    h.x = f2b(v.x); l.x = f2b(v.x - b2f(h.x));
    h.y = f2b(v.y); l.y = f2b(v.y - b2f(h.y));
    h.z = f2b(v.z); l.z = f2b(v.z - b2f(h.z));
    h.w = f2b(v.w); l.w = f2b(v.w - b2f(h.w));
    reinterpret_cast<ushort4*>(Whi + (size_t)o * Hz)[kq] = h;
    reinterpret_cast<ushort4*>(Wlo + (size_t)o * Hz)[kq] = l;
}

// ---------------------------------------------------------------------------
// f32 -> bf16 with zero padding (fc_W)
__global__ __launch_bounds__(256) void cvt_bf16_pad4(const float* __restrict__ s,
                                                     ushort* __restrict__ d,
                                                     int n4src, int n4dst) {
    int i = blockIdx.x * 256 + threadIdx.x;
    if (i >= n4dst) return;
    ushort4 o;
    if (i < n4src) {
        float4 v = reinterpret_cast<const float4*>(s)[i];
        o.x = f2b(v.x); o.y = f2b(v.y); o.z = f2b(v.z); o.w = f2b(v.w);
    } else {
        o.x = o.y = o.z = o.w = 0;
    }
    reinterpret_cast<ushort4*>(d)[i] = o;
}

// ---------------------------------------------------------------------------
// split fp32 h0 -> bf16 hi/lo
__global__ __launch_bounds__(256) void split_h(const float* __restrict__ h,
                                               ushort* __restrict__ hi,
                                               ushort* __restrict__ lo) {
    int i = blockIdx.x * 256 + threadIdx.x;          // Bz*Hz/4
    if (i >= Bz * Hz / 4) return;
    float4 v = reinterpret_cast<const float4*>(h)[i];
    ushort4 a, b;
    a.x = f2b(v.x); b.x = f2b(v.x - b2f(a.x));
    a.y = f2b(v.y); b.y = f2b(v.y - b2f(a.y));
    a.z = f2b(v.z); b.z = f2b(v.z - b2f(a.z));
    a.w = f2b(v.w); b.w = f2b(v.w - b2f(a.w));
    reinterpret_cast<ushort4*>(hi)[i] = a;
    reinterpret_cast<ushort4*>(lo)[i] = b;
}

// ---------------------------------------------------------------------------
// bf16 MFMA GEMM (m97 structure): C[m][n] = A[m].B[n] + bias[n]
// A [M][K] bf16, B [>=Ntiles*128][K] bf16, M mult of 128, K mult of 32.
// Nb = store bound, ldc = C row stride.
__global__ __launch_bounds__(256) void gemm_mfma(
    const ushort* __restrict__ A,
    const ushort* __restrict__ B,
    const float* __restrict__ bias,
    float* __restrict__ C,
    int Nb, int ldc, int K)
{
    __shared__ short Al[128 * 32];
    __shared__ short Bl[128 * 32];
    const int tid  = threadIdx.x;
    const int w    = tid >> 6;
    const int lane = tid & 63;
    const int m0 = blockIdx.y * 128;
    const int n0 = blockIdx.x * 128;
    const int wr = w >> 1, wc = w & 1;

    f32x4 acc[4][4] = {};

    const int srow = w * 32 + (lane >> 2);
    const int scol = (lane & 3) * 16;
    const char* Ag = (const char*)(A + (size_t)(m0 + srow) * K) + scol;
    const char* Bg = (const char*)(B + (size_t)(n0 + srow) * K) + scol;
    const size_t rstep = (size_t)16 * K * 2;
    short* Alb = Al + (w * 32) * 32;
    short* Blb = Bl + (w * 32) * 32;

    const int ko = (lane >> 4) * 8;
    const int fr = lane & 15;

    for (int k0 = 0; k0 < K; k0 += 32) {
        const size_t kb = (size_t)k0 * 2;
        gload_lds16(Ag + kb,         Alb);
        gload_lds16(Ag + kb + rstep, Alb + 16 * 32);
        gload_lds16(Bg + kb,         Blb);
        gload_lds16(Bg + kb + rstep, Blb + 16 * 32);
        __syncthreads();

        bf16x8 af[4], bf[4];
#pragma unroll
        for (int i = 0; i < 4; ++i)
            af[i] = *reinterpret_cast<const bf16x8*>(&Al[(wr * 64 + i * 16 + fr) * 32 + ko]);
#pragma unroll
        for (int j = 0; j < 4; ++j)
            bf[j] = *reinterpret_cast<const bf16x8*>(&Bl[(wc * 64 + j * 16 + fr) * 32 + ko]);
#pragma unroll
        for (int i = 0; i < 4; ++i)
#pragma unroll
            for (int j = 0; j < 4; ++j)
                acc[i][j] = __builtin_amdgcn_mfma_f32_16x16x32_bf16(
                    af[i], bf[j], acc[i][j], 0, 0, 0);
        __syncthreads();
    }

    const int r0 = (lane >> 4) * 4;
#pragma unroll
    for (int i = 0; i < 4; ++i) {
        int row = m0 + wr * 64 + i * 16 + r0;
#pragma unroll
        for (int j = 0; j < 4; ++j) {
            int col = n0 + wc * 64 + j * 16 + fr;
            if (col < Nb) {
                float bb = bias ? bias[col] : 0.f;
#pragma unroll
                for (int r = 0; r < 4; ++r)
                    C[(size_t)(row + r) * ldc + col] = acc[i][j][r] + bb;
            }
        }
    }
}

// ---------------------------------------------------------------------------
// fp32 tiled GEMM (init h0/c0 only)
__global__ __launch_bounds__(256) void gemm_rr(
    const float* __restrict__ A, int lda,
    const float* __restrict__ B, int ldb,
    const float* __restrict__ bias1,
    float* __restrict__ C, int ldc,
    int M, int N, int K)
{
    __shared__ float As[64][33];
    __shared__ float Bs[64][33];
    const int m0 = blockIdx.y * 64;
    const int n0 = blockIdx.x * 64;
    const int tid = threadIdx.x;
    const int tx = tid & 15, ty = tid >> 4;
    float acc[4][4] = {};

    for (int k0 = 0; k0 < K; k0 += 32) {
#pragma unroll
        for (int i = 0; i < 2; ++i) {
            int e  = tid + i * 256;
            int r  = e >> 3;
            int cc = (e & 7) << 2;
            int m = m0 + r;
            float4 va = {0.f, 0.f, 0.f, 0.f};
            if (m < M)
                va = *reinterpret_cast<const float4*>(A + (size_t)m * lda + k0 + cc);
            As[r][cc + 0] = va.x; As[r][cc + 1] = va.y;
            As[r][cc + 2] = va.z; As[r][cc + 3] = va.w;
            int n = n0 + r;
            float4 vb = {0.f, 0.f, 0.f, 0.f};
            if (n < N)
                vb = *reinterpret_cast<const float4*>(B + (size_t)n * ldb + k0 + cc);
            Bs[r][cc + 0] = vb.x; Bs[r][cc + 1] = vb.y;
            Bs[r][cc + 2] = vb.z; Bs[r][cc + 3] = vb.w;
        }
        __syncthreads();
#pragma unroll
        for (int kk = 0; kk < 32; ++kk) {
            float a[4], bb[4];
#pragma unroll
            for (int i = 0; i < 4; ++i) a[i] = As[ty * 4 + i][kk];
#pragma unroll
            for (int j = 0; j < 4; ++j) bb[j] = Bs[tx * 4 + j][kk];
#pragma unroll
            for (int i = 0; i < 4; ++i)
#pragma unroll
                for (int j = 0; j < 4; ++j)
                    acc[i][j] += a[i] * bb[j];
        }
        __syncthreads();
    }

#pragma unroll
    for (int i = 0; i < 4; ++i) {
        int m = m0 + ty * 4 + i;
        if (m >= M) continue;
#pragma unroll
        for (int j = 0; j < 4; ++j) {
            int n = n0 + tx * 4 + j;
            if (n >= N) continue;
            C[(size_t)m * ldc + n] = acc[i][j] + (bias1 ? bias1[n] : 0.f);
        }
    }
}

// ---------------------------------------------------------------------------
// One LSTM step, MFMA. gates[128][2048-permuted] = sum of 3 hi/lo segments,
// then fused gate nonlinearity + c/h update.
// Grid 32 blocks x 256 thr. Block: all 128 batch rows x 64 permuted cols
// (= 16 h indices). BK=128, XOR-swizzled LDS (src-side pre-swizzle, rule 21).
__global__ __launch_bounds__(256) void lstm_step_mfma(
    const float* __restrict__ xg,
    const ushort* __restrict__ Whi, const ushort* __restrict__ Wlo,
    const ushort* __restrict__ hin_hi, const ushort* __restrict__ hin_lo,
    ushort* __restrict__ hout_hi, ushort* __restrict__ hout_lo,
    float* __restrict__ c, ushort* __restrict__ hs_b, int t)
{
    __shared__ char smem[49152];
    short* Al = (short*)smem;              // [128][128] bf16, swizzled
    short* Bl = (short*)(smem + 32768);    // [64][128]
    float* Cl = (float*)smem;              // [128][65] epilogue overlay

    const int tid = threadIdx.x;
    const int w = tid >> 6;
    const int lane = tid & 63;
    const int hi = lane >> 4;
    const int fr = lane & 15;
    const int n0 = blockIdx.x * 64;

    f32x4 acc[2][4] = {};
    const int scol = fr * 16;              // byte slot within 256B row

    const ushort* Aseg[3] = {hin_hi, hin_hi, hin_lo};
    const ushort* Bseg[3] = {Whi, Wlo, Whi};

#pragma unroll
    for (int s = 0; s < 3; ++s) {
        const char* Ab = (const char*)Aseg[s];
        const char* Bb = (const char*)(Bseg[s] + (size_t)n0 * Hz);
#pragma unroll
        for (int k0 = 0; k0 < Hz; k0 += 128) {
            // stage A (128 rows x 256B): 8 instrs/wave, rows w*32+i*4+hi
#pragma unroll
            for (int i = 0; i < 8; ++i) {
                int row = w * 32 + i * 4 + hi;
                gload_lds16(Ab + (size_t)row * 1024 + k0 * 2 + (scol ^ ((row & 7) << 4)),
                            (char*)Al + (w * 32 + i * 4) * 256);
            }
            // stage B (64 rows): 4 instrs/wave
#pragma unroll
            for (int i = 0; i < 4; ++i) {
                int row = w * 16 + i * 4 + hi;
                gload_lds16(Bb + (size_t)row * 1024 + k0 * 2 + (scol ^ ((row & 7) << 4)),
                            (char*)Bl + (w * 16 + i * 4) * 256);
            }
            __syncthreads();

            bf16x8 af[2][4], bf[4][4];
#pragma unroll
            for (int i = 0; i < 2; ++i) {
                int row = w * 32 + i * 16 + fr;
#pragma unroll
                for (int ks = 0; ks < 4; ++ks) {
                    int kb = ks * 64 + hi * 16;
                    af[i][ks] = *reinterpret_cast<const bf16x8*>(
                        (const char*)Al + row * 256 + (kb ^ ((row & 7) << 4)));
                }
            }
#pragma unroll
            for (int j = 0; j < 4; ++j) {
                int row = j * 16 + fr;
#pragma unroll
                for (int ks = 0; ks < 4; ++ks) {
                    int kb = ks * 64 + hi * 16;
                    bf[j][ks] = *reinterpret_cast<const bf16x8*>(
                        (const char*)Bl + row * 256 + (kb ^ ((row & 7) << 4)));
                }
            }
#pragma unroll
            for (int ks = 0; ks < 4; ++ks)
#pragma unroll
                for (int i = 0; i < 2; ++i)
#pragma unroll
                    for (int j = 0; j < 4; ++j)
                        acc[i][j] = __builtin_amdgcn_mfma_f32_16x16x32_bf16(
                            af[i][ks], bf[j][ks], acc[i][j], 0, 0, 0);
            __syncthreads();
        }
    }

    // gates -> LDS (cross-lane gate regroup)
#pragma unroll
    for (int i = 0; i < 2; ++i)
#pragma unroll
        for (int j = 0; j < 4; ++j)
#pragma unroll
            for (int r = 0; r < 4; ++r)
                Cl[(w * 32 + i * 16 + hi * 4 + r) * 65 + j * 16 + fr] = acc[i][j][r];
    __syncthreads();

    // fused gate nonlinearity + state update: 2048 outputs, 8 per thread
#pragma unroll
    for (int it = 0; it < 8; ++it) {
        int idx = tid + it * 256;
        int jl = idx & 15;
        int m  = idx >> 4;
        float gi = Cl[m * 65 + 4 * jl + 0];
        float gf = Cl[m * 65 + 4 * jl + 1];
        float gg = Cl[m * 65 + 4 * jl + 2];
        float go = Cl[m * 65 + 4 * jl + 3];
        float4 x4 = *reinterpret_cast<const float4*>(
            xg + ((size_t)m * TM + t) * G4 + n0 + 4 * jl);
        gi += x4.x; gf += x4.y; gg += x4.z; go += x4.w;
        float ig = 1.f / (1.f + expf(-gi));
        float fg = 1.f / (1.f + expf(-gf));
        float gt = tanhf(gg);
        float og = 1.f / (1.f + expf(-go));
        int jg = (n0 >> 2) + jl;
        size_t cix = (size_t)m * Hz + jg;
        float cn = fg * c[cix] + ig * gt;
        c[cix] = cn;
        float h = og * tanhf(cn);
        ushort hh = f2b(h);
        ushort hl = f2b(h - b2f(hh));
        hout_hi[cix] = hh;
        hout_lo[cix] = hl;
        hs_b[((size_t)m * TM + t) * Hz + jg] = hh;
    }
}

// ---------------------------------------------------------------------------
extern "C" void kernel_launch(void* const* d_in, const int* in_sizes, int n_in,
                              void* d_out, int out_size, void* d_ws, size_t ws_size,
                              hipStream_t stream) {
    const float* features = (const float*)d_in[0];
    const int*   captions = (const int*)d_in[1];
    const float* emb_W    = (const float*)d_in[2];
    const float* W_ih     = (const float*)d_in[3];
    const float* W_hh     = (const float*)d_in[4];
    const float* b_ih     = (const float*)d_in[5];
    const float* b_hh     = (const float*)d_in[6];
    const float* Wh       = (const float*)d_in[7];
    const float* bh       = (const float*)d_in[8];
    const float* Wc       = (const float*)d_in[9];
    const float* bc       = (const float*)d_in[10];
    const float* fc_W     = (const float*)d_in[11];
    const float* fc_b     = (const float*)d_in[12];
    float* out = (float*)d_out;

    // workspace carve-up
    float* w    = (float*)d_ws;
    float* mean = w;                            // 262144 f
    float* h0   = mean + Bz * Fz;               // 65536 f
    float* cbuf = h0 + Bz * Hz;                 // 65536 f
    float* xg   = cbuf + Bz * Hz;               // 3968*2048 f
    float* bP   = xg + (size_t)Mrows * G4;      // 2048 f
    int*  gidx  = (int*)(bP + G4);              // 3968 i
    ushort* embg = (ushort*)(gidx + Mrows);     // 3968*512
    ushort* WihP = embg + (size_t)Mrows * Ez;   // 2048*512
    ushort* Whi  = WihP + (size_t)G4 * Ez;      // 2048*512
    ushort* Wlo  = Whi + (size_t)G4 * Hz;       // 2048*512
    ushort* fcWb = Wlo + (size_t)G4 * Hz;       // 10112*512
    ushort* hsb  = fcWb + (size_t)NPAD * Hz;    // 3968*512
    ushort* haHi = hsb + (size_t)Mrows * Hz;    // 128*512
    ushort* haLo = haHi + Bz * Hz;
    ushort* hbHi = haLo + Bz * Hz;
    ushort* hbLo = hbHi + Bz * Hz;

    build_gidx<<<(Mrows + 255) / 256, 256, 0, stream>>>(captions, gidx);
    meanpool<<<(Bz * Fz / 4) / 256, 256, 0, stream>>>(features, mean);
    gather_cvt_emb<<<(Mrows * (Ez / 4) + 255) / 256, 256, 0, stream>>>(emb_W, gidx, embg);
    permute_wih<<<(G4 * (Ez / 4)) / 256, 256, 0, stream>>>(W_ih, b_ih, b_hh, WihP, bP);
    permute_whh_split<<<(G4 * (Hz / 4)) / 256, 256, 0, stream>>>(W_hh, Whi, Wlo);
    cvt_bf16_pad4<<<(NPAD * Hz / 4 + 255) / 256, 256, 0, stream>>>(
        fc_W, fcWb, Vz * Hz / 4, NPAD * Hz / 4);

    // init h0/c0 (fp32)
    gemm_rr<<<dim3(Hz / 64, Bz / 64), 256, 0, stream>>>(
        mean, Fz, Wh, Fz, bh, h0, Hz, Bz, Hz, Fz);
    gemm_rr<<<dim3(Hz / 64, Bz / 64), 256, 0, stream>>>(
        mean, Fz, Wc, Fz, bc, cbuf, Hz, Bz, Hz, Fz);
    split_h<<<(Bz * Hz / 4 + 255) / 256, 256, 0, stream>>>(h0, haHi, haLo);

    // x-side gates, permuted layout, bf16 MFMA
    gemm_mfma<<<dim3(G4 / 128, Mrows / 128), 256, 0, stream>>>(
        embg, WihP, bP, xg, G4, G4, Ez);

    // recurrence
    for (int t = 0; t < TM; ++t) {
        const ushort* ih = (t & 1) ? hbHi : haHi;
        const ushort* il = (t & 1) ? hbLo : haLo;
        ushort* oh = (t & 1) ? haHi : hbHi;
        ushort* ol = (t & 1) ? haLo : hbLo;
        lstm_step_mfma<<<G4 / 64, 256, 0, stream>>>(
            xg, Whi, Wlo, ih, il, oh, ol, cbuf, hsb, t);
    }

    // output projection
    gemm_mfma<<<dim3(NPAD / 128, Mrows / 128), 256, 0, stream>>>(
        hsb, fcWb, fc_b, out, Vz, Vz, Hz);
}

// Round 4
// 1056.139 us; speedup vs baseline: 2.2100x; 1.1219x over previous
//
#include <hip/hip_runtime.h>
#include <hip/hip_bf16.h>
#include <cstddef>

// Problem constants
#define Bz 128
#define Pz 196
#define Fz 2048
#define Ez 512
#define Hz 512
#define Vz 10000
#define Tz 32
#define TM 31                 // time steps
#define Mrows (Bz * TM)       // 3968
#define G4 (4 * Hz)           // 2048 gate width
#define NPAD 10112            // 79*128 padded vocab
#define NBLK 64               // persistent LSTM blocks
#define NCOL 32               // gate cols per block

typedef __attribute__((ext_vector_type(8))) short bf16x8;
typedef __attribute__((ext_vector_type(4))) float f32x4;

__device__ __forceinline__ void gload_lds16(const void* g, void* l) {
    __builtin_amdgcn_global_load_lds(
        (const __attribute__((address_space(1))) unsigned int*)g,
        (__attribute__((address_space(3))) unsigned int*)l, 16, 0, 0);
}
__device__ __forceinline__ ushort f2b(float x) {
    __hip_bfloat16 b = __float2bfloat16(x);
    return *reinterpret_cast<ushort*>(&b);
}
__device__ __forceinline__ float b2f(ushort u) {
    __hip_bfloat16 b = *reinterpret_cast<__hip_bfloat16*>(&u);
    return __bfloat162float(b);
}

// ---------------------------------------------------------------------------
__global__ __launch_bounds__(64) void zero_bar(int* bar) {
    if (threadIdx.x == 0) *bar = 0;
}

// ---------------------------------------------------------------------------
__global__ __launch_bounds__(256) void build_gidx(const int* __restrict__ cap,
                                                  int* __restrict__ gidx) {
    int m = blockIdx.x * 256 + threadIdx.x;
    if (m < Mrows) {
        int b = m / TM;
        int t = m - b * TM;
        gidx[m] = cap[b * Tz + t];
    }
}

// ---------------------------------------------------------------------------
__global__ __launch_bounds__(256) void meanpool(const float* __restrict__ feat,
                                                float* __restrict__ mean) {
    int idx = blockIdx.x * 256 + threadIdx.x;
    int b = idx >> 9;
    int q = idx & 511;
    const float4* base = reinterpret_cast<const float4*>(feat) +
                         (size_t)b * Pz * (Fz / 4) + q;
    float4 acc = {0.f, 0.f, 0.f, 0.f};
    for (int p = 0; p < Pz; ++p) {
        float4 v = base[(size_t)p * (Fz / 4)];
        acc.x += v.x; acc.y += v.y; acc.z += v.z; acc.w += v.w;
    }
    const float s = 1.0f / (float)Pz;
    acc.x *= s; acc.y *= s; acc.z *= s; acc.w *= s;
    reinterpret_cast<float4*>(mean)[idx] = acc;
}

// ---------------------------------------------------------------------------
__global__ __launch_bounds__(256) void gather_cvt_emb(const float* __restrict__ emb,
                                                      const int* __restrict__ gidx,
                                                      ushort* __restrict__ out) {
    int idx = blockIdx.x * 256 + threadIdx.x;        // Mrows * 128
    if (idx >= Mrows * (Ez / 4)) return;
    int m = idx >> 7, kq = idx & 127;
    float4 v = reinterpret_cast<const float4*>(emb + (size_t)gidx[m] * Ez)[kq];
    ushort4 o = {f2b(v.x), f2b(v.y), f2b(v.z), f2b(v.w)};
    reinterpret_cast<ushort4*>(out + (size_t)m * Ez)[kq] = o;
}

// ---------------------------------------------------------------------------
// permute W_ih rows g*512+j -> 4j+g, convert bf16; also bP[4j+g]=b_ih+b_hh
__global__ __launch_bounds__(256) void permute_wih(const float* __restrict__ W,
                                                   const float* __restrict__ b1,
                                                   const float* __restrict__ b2,
                                                   ushort* __restrict__ WP,
                                                   float* __restrict__ bP) {
    int idx = blockIdx.x * 256 + threadIdx.x;        // 2048*128
    int o = idx >> 7, kq = idx & 127;
    int j = o >> 2, g = o & 3;
    int in = g * Hz + j;
    float4 v = reinterpret_cast<const float4*>(W + (size_t)in * Ez)[kq];
    ushort4 u = {f2b(v.x), f2b(v.y), f2b(v.z), f2b(v.w)};
    reinterpret_cast<ushort4*>(WP + (size_t)o * Ez)[kq] = u;
    if (kq == 0) bP[o] = b1[in] + b2[in];
}

// ---------------------------------------------------------------------------
// permute W_hh rows g*512+j -> 4j+g, bf16 (hi only)
__global__ __launch_bounds__(256) void permute_whh(const float* __restrict__ W,
                                                   ushort* __restrict__ Whi) {
    int idx = blockIdx.x * 256 + threadIdx.x;        // 2048*128
    int o = idx >> 7, kq = idx & 127;
    int j = o >> 2, g = o & 3;
    int in = g * Hz + j;
    float4 v = reinterpret_cast<const float4*>(W + (size_t)in * Hz)[kq];
    ushort4 h = {f2b(v.x), f2b(v.y), f2b(v.z), f2b(v.w)};
    reinterpret_cast<ushort4*>(Whi + (size_t)o * Hz)[kq] = h;
}

// ---------------------------------------------------------------------------
__global__ __launch_bounds__(256) void cvt_bf16_pad4(const float* __restrict__ s,
                                                     ushort* __restrict__ d,
                                                     int n4src, int n4dst) {
    int i = blockIdx.x * 256 + threadIdx.x;
    if (i >= n4dst) return;
    ushort4 o;
    if (i < n4src) {
        float4 v = reinterpret_cast<const float4*>(s)[i];
        o.x = f2b(v.x); o.y = f2b(v.y); o.z = f2b(v.z); o.w = f2b(v.w);
    } else {
        o.x = o.y = o.z = o.w = 0;
    }
    reinterpret_cast<ushort4*>(d)[i] = o;
}

// ---------------------------------------------------------------------------
// split-K fp32 init GEMM: partial[kz][m][n] = mean[m] . [Wh;Wc][n] over K-slice
__global__ __launch_bounds__(256) void initk(
    const float* __restrict__ mean,
    const float* __restrict__ Wh, const float* __restrict__ Wc,
    float* __restrict__ partial)
{
    __shared__ float As[64][33];
    __shared__ float Bs2[64][33];
    const int n0 = blockIdx.x * 64;    // 0..960 (1024 = Wh|Wc stacked)
    const int m0 = blockIdx.y * 64;    // 0,64
    const int kz = blockIdx.z;         // 0..7
    const int tid = threadIdx.x;
    const int tx = tid & 15, ty = tid >> 4;
    float acc[4][4] = {};

    for (int k0 = kz * 256; k0 < kz * 256 + 256; k0 += 32) {
#pragma unroll
        for (int i = 0; i < 2; ++i) {
            int e  = tid + i * 256;
            int r  = e >> 3;
            int cc = (e & 7) << 2;
            float4 va = *reinterpret_cast<const float4*>(
                mean + (size_t)(m0 + r) * Fz + k0 + cc);
            As[r][cc + 0] = va.x; As[r][cc + 1] = va.y;
            As[r][cc + 2] = va.z; As[r][cc + 3] = va.w;
            int n = n0 + r;
            const float* Brow = (n < Hz) ? (Wh + (size_t)n * Fz)
                                         : (Wc + (size_t)(n - Hz) * Fz);
            float4 vb = *reinterpret_cast<const float4*>(Brow + k0 + cc);
            Bs2[r][cc + 0] = vb.x; Bs2[r][cc + 1] = vb.y;
            Bs2[r][cc + 2] = vb.z; Bs2[r][cc + 3] = vb.w;
        }
        __syncthreads();
#pragma unroll
        for (int kk = 0; kk < 32; ++kk) {
            float a[4], bb[4];
#pragma unroll
            for (int i = 0; i < 4; ++i) a[i] = As[ty * 4 + i][kk];
#pragma unroll
            for (int j = 0; j < 4; ++j) bb[j] = Bs2[tx * 4 + j][kk];
#pragma unroll
            for (int i = 0; i < 4; ++i)
#pragma unroll
                for (int j = 0; j < 4; ++j)
                    acc[i][j] += a[i] * bb[j];
        }
        __syncthreads();
    }
#pragma unroll
    for (int i = 0; i < 4; ++i)
#pragma unroll
        for (int j = 0; j < 4; ++j)
            partial[((size_t)kz * 128 + m0 + ty * 4 + i) * 1024 + n0 + tx * 4 + j]
                = acc[i][j];
}

// ---------------------------------------------------------------------------
// reduce split-K partials; n<512 -> h0 (bf16 hi/lo), n>=512 -> c0 fp32
__global__ __launch_bounds__(256) void init_reduce(
    const float* __restrict__ partial,
    const float* __restrict__ bh, const float* __restrict__ bc,
    ushort* __restrict__ haHi, ushort* __restrict__ haLo,
    float* __restrict__ c0f)
{
    int idx = blockIdx.x * 256 + threadIdx.x;
    if (idx >= 128 * 1024) return;
    int m = idx >> 10, n = idx & 1023;
    float s = 0.f;
#pragma unroll
    for (int z = 0; z < 8; ++z)
        s += partial[((size_t)z * 128 + m) * 1024 + n];
    if (n < Hz) {
        s += bh[n];
        ushort hh = f2b(s);
        haHi[(size_t)m * Hz + n] = hh;
        haLo[(size_t)m * Hz + n] = f2b(s - b2f(hh));
    } else {
        c0f[(size_t)m * Hz + (n - Hz)] = s + bc[n - Hz];
    }
}

// ---------------------------------------------------------------------------
// bf16 MFMA GEMM (m97 structure), used for xg and fc
__global__ __launch_bounds__(256) void gemm_mfma(
    const ushort* __restrict__ A,
    const ushort* __restrict__ B,
    const float* __restrict__ bias,
    float* __restrict__ C,
    int Nb, int ldc, int K)
{
    __shared__ short Al[128 * 32];
    __shared__ short Bl[128 * 32];
    const int tid  = threadIdx.x;
    const int w    = tid >> 6;
    const int lane = tid & 63;
    const int m0 = blockIdx.y * 128;
    const int n0 = blockIdx.x * 128;
    const int wr = w >> 1, wc = w & 1;

    f32x4 acc[4][4] = {};

    const int srow = w * 32 + (lane >> 2);
    const int scol = (lane & 3) * 16;
    const char* Ag = (const char*)(A + (size_t)(m0 + srow) * K) + scol;
    const char* Bg = (const char*)(B + (size_t)(n0 + srow) * K) + scol;
    const size_t rstep = (size_t)16 * K * 2;
    short* Alb = Al + (w * 32) * 32;
    short* Blb = Bl + (w * 32) * 32;

    const int ko = (lane >> 4) * 8;
    const int fr = lane & 15;

    for (int k0 = 0; k0 < K; k0 += 32) {
        const size_t kb = (size_t)k0 * 2;
        gload_lds16(Ag + kb,         Alb);
        gload_lds16(Ag + kb + rstep, Alb + 16 * 32);
        gload_lds16(Bg + kb,         Blb);
        gload_lds16(Bg + kb + rstep, Blb + 16 * 32);
        __syncthreads();

        bf16x8 af[4], bf[4];
#pragma unroll
        for (int i = 0; i < 4; ++i)
            af[i] = *reinterpret_cast<const bf16x8*>(&Al[(wr * 64 + i * 16 + fr) * 32 + ko]);
#pragma unroll
        for (int j = 0; j < 4; ++j)
            bf[j] = *reinterpret_cast<const bf16x8*>(&Bl[(wc * 64 + j * 16 + fr) * 32 + ko]);
#pragma unroll
        for (int i = 0; i < 4; ++i)
#pragma unroll
            for (int j = 0; j < 4; ++j)
                acc[i][j] = __builtin_amdgcn_mfma_f32_16x16x32_bf16(
                    af[i], bf[j], acc[i][j], 0, 0, 0);
        __syncthreads();
    }

    const int r0 = (lane >> 4) * 4;
#pragma unroll
    for (int i = 0; i < 4; ++i) {
        int row = m0 + wr * 64 + i * 16 + r0;
#pragma unroll
        for (int j = 0; j < 4; ++j) {
            int col = n0 + wc * 64 + j * 16 + fr;
            if (col < Nb) {
                float bb = bias ? bias[col] : 0.f;
#pragma unroll
                for (int r = 0; r < 4; ++r)
                    C[(size_t)(row + r) * ldc + col] = acc[i][j][r] + bb;
            }
        }
    }
}

// ---------------------------------------------------------------------------
// Persistent LSTM: 64 blocks x 256 thr, one grid barrier per step.
// Block owns NCOL=32 permuted gate cols (8 h-indices). W panel (bf16-hi,
// XOR-swizzled) resident in LDS; c in registers; A (h hi/lo) fragments
// loaded directly global->VGPR in MFMA layout.
__global__ __launch_bounds__(256) void lstm_persist(
    const float* __restrict__ xg,
    const ushort* __restrict__ Whi,
    ushort* haHi, ushort* haLo, ushort* hbHi, ushort* hbLo,
    const float* __restrict__ c0f,
    ushort* __restrict__ hsb,
    int* bar)
{
    __shared__ short Bs[NCOL * 512];      // 32KB swizzled W panel
    __shared__ float Cl[128][33];         // gate regroup

    const int tid  = threadIdx.x;
    const int w    = tid >> 6;
    const int lane = tid & 63;
    const int fr   = lane & 15;
    const int hi4  = lane >> 4;           // 0..3
    const int n0   = blockIdx.x * NCOL;
    const int j0   = n0 >> 2;             // 8 h-indices per block
    const int m0w  = w * 32;

    // load W panel (rows n0..n0+31, K=512) into LDS, XOR-swizzled
#pragma unroll
    for (int i = 0; i < 8; ++i) {
        int cid = i * 256 + tid;          // 2048 16B chunks
        int row = cid >> 6;
        int ch  = cid & 63;
        bf16x8 v = *reinterpret_cast<const bf16x8*>(
            Whi + (size_t)(n0 + row) * Hz + ch * 8);
        int byte = row * 1024 + ((ch * 16) ^ ((row & 7) << 4));
        *reinterpret_cast<bf16x8*>((char*)Bs + byte) = v;
    }
    float creg[8];
    if (tid < 128) {
        const float* cp = c0f + (size_t)tid * Hz + j0;
#pragma unroll
        for (int jl = 0; jl < 8; ++jl) creg[jl] = cp[jl];
    }
    __syncthreads();

    for (int t = 0; t < TM; ++t) {
        const ushort* Ah = (t & 1) ? hbHi : haHi;
        const ushort* Alo = (t & 1) ? hbLo : haLo;
        ushort* Oh = (t & 1) ? haHi : hbHi;
        ushort* Ol = (t & 1) ? haLo : hbLo;

        f32x4 acc[2][2] = {};
#pragma unroll 4
        for (int kc = 0; kc < 16; ++kc) {
            const int kbyte = kc * 64 + hi4 * 16;
            bf16x8 b0 = *reinterpret_cast<const bf16x8*>(
                (const char*)Bs + fr * 1024 + (kbyte ^ ((fr & 7) << 4)));
            bf16x8 b1 = *reinterpret_cast<const bf16x8*>(
                (const char*)Bs + (16 + fr) * 1024 + (kbyte ^ ((fr & 7) << 4)));
            const size_t koff = (size_t)kc * 32 + hi4 * 8;
            bf16x8 ah0 = *reinterpret_cast<const bf16x8*>(Ah  + (size_t)(m0w + fr) * Hz + koff);
            bf16x8 ah1 = *reinterpret_cast<const bf16x8*>(Ah  + (size_t)(m0w + 16 + fr) * Hz + koff);
            bf16x8 al0 = *reinterpret_cast<const bf16x8*>(Alo + (size_t)(m0w + fr) * Hz + koff);
            bf16x8 al1 = *reinterpret_cast<const bf16x8*>(Alo + (size_t)(m0w + 16 + fr) * Hz + koff);
            acc[0][0] = __builtin_amdgcn_mfma_f32_16x16x32_bf16(ah0, b0, acc[0][0], 0, 0, 0);
            acc[0][1] = __builtin_amdgcn_mfma_f32_16x16x32_bf16(ah0, b1, acc[0][1], 0, 0, 0);
            acc[1][0] = __builtin_amdgcn_mfma_f32_16x16x32_bf16(ah1, b0, acc[1][0], 0, 0, 0);
            acc[1][1] = __builtin_amdgcn_mfma_f32_16x16x32_bf16(ah1, b1, acc[1][1], 0, 0, 0);
            acc[0][0] = __builtin_amdgcn_mfma_f32_16x16x32_bf16(al0, b0, acc[0][0], 0, 0, 0);
            acc[0][1] = __builtin_amdgcn_mfma_f32_16x16x32_bf16(al0, b1, acc[0][1], 0, 0, 0);
            acc[1][0] = __builtin_amdgcn_mfma_f32_16x16x32_bf16(al1, b0, acc[1][0], 0, 0, 0);
            acc[1][1] = __builtin_amdgcn_mfma_f32_16x16x32_bf16(al1, b1, acc[1][1], 0, 0, 0);
        }

        // regroup gates into Cl[m][col]
#pragma unroll
        for (int i = 0; i < 2; ++i)
#pragma unroll
            for (int j = 0; j < 2; ++j)
#pragma unroll
                for (int r = 0; r < 4; ++r)
                    Cl[m0w + i * 16 + hi4 * 4 + r][j * 16 + fr] = acc[i][j][r];
        __syncthreads();

        if (tid < 128) {
            const float* xr = xg + ((size_t)tid * TM + t) * G4 + n0;
            bf16x8 vh, vl;
#pragma unroll
            for (int jl = 0; jl < 8; ++jl) {
                float gi = Cl[tid][4 * jl + 0] + xr[4 * jl + 0];
                float gf = Cl[tid][4 * jl + 1] + xr[4 * jl + 1];
                float gg = Cl[tid][4 * jl + 2] + xr[4 * jl + 2];
                float go = Cl[tid][4 * jl + 3] + xr[4 * jl + 3];
                float ig = 1.f / (1.f + expf(-gi));
                float fg = 1.f / (1.f + expf(-gf));
                float gt = tanhf(gg);
                float og = 1.f / (1.f + expf(-go));
                float cn = fg * creg[jl] + ig * gt;
                creg[jl] = cn;
                float h = og * tanhf(cn);
                ushort hh = f2b(h);
                vh[jl] = (short)hh;
                vl[jl] = (short)f2b(h - b2f(hh));
            }
            *reinterpret_cast<bf16x8*>(Oh + (size_t)tid * Hz + j0) = vh;
            *reinterpret_cast<bf16x8*>(Ol + (size_t)tid * Hz + j0) = vl;
            *reinterpret_cast<bf16x8*>(hsb + ((size_t)tid * TM + t) * Hz + j0) = vh;
        }

        if (t < TM - 1) {
            // grid barrier (release fences -> arrive -> spin -> acquire fences)
            __threadfence();
            __syncthreads();
            if (tid == 0) {
                atomicAdd(bar, 1);
                const int target = NBLK * (t + 1);
                while (atomicAdd(bar, 0) < target) __builtin_amdgcn_s_sleep(2);
            }
            __syncthreads();
            __threadfence();
        }
    }
}

// ---------------------------------------------------------------------------
extern "C" void kernel_launch(void* const* d_in, const int* in_sizes, int n_in,
                              void* d_out, int out_size, void* d_ws, size_t ws_size,
                              hipStream_t stream) {
    const float* features = (const float*)d_in[0];
    const int*   captions = (const int*)d_in[1];
    const float* emb_W    = (const float*)d_in[2];
    const float* W_ih     = (const float*)d_in[3];
    const float* W_hh     = (const float*)d_in[4];
    const float* b_ih     = (const float*)d_in[5];
    const float* b_hh     = (const float*)d_in[6];
    const float* Wh       = (const float*)d_in[7];
    const float* bh       = (const float*)d_in[8];
    const float* Wc       = (const float*)d_in[9];
    const float* bc       = (const float*)d_in[10];
    const float* fc_W     = (const float*)d_in[11];
    const float* fc_b     = (const float*)d_in[12];
    float* out = (float*)d_out;

    // workspace carve-up
    float* w    = (float*)d_ws;
    float* mean = w;                            // 262144 f
    float* xg   = mean + Bz * Fz;               // 8,126,464 f (partial overlaid)
    float* partial = xg;                        // [8][128][1024] f, used pre-xg
    float* c0f  = xg + (size_t)Mrows * G4;      // 65536 f
    float* bP   = c0f + Bz * Hz;                // 2048 f
    int*  gidx  = (int*)(bP + G4);              // 3968 i
    int*  bar   = gidx + Mrows;                 // barrier counter (+pad)
    ushort* embg = (ushort*)(bar + 64);         // 3968*512
    ushort* WihP = embg + (size_t)Mrows * Ez;   // 2048*512
    ushort* Whi  = WihP + (size_t)G4 * Ez;      // 2048*512
    ushort* fcWb = Whi + (size_t)G4 * Hz;       // 10112*512
    ushort* hsb  = fcWb + (size_t)NPAD * Hz;    // 3968*512
    ushort* haHi = hsb + (size_t)Mrows * Hz;    // 128*512 each below
    ushort* haLo = haHi + Bz * Hz;
    ushort* hbHi = haLo + Bz * Hz;
    ushort* hbLo = hbHi + Bz * Hz;

    zero_bar<<<1, 64, 0, stream>>>(bar);
    build_gidx<<<(Mrows + 255) / 256, 256, 0, stream>>>(captions, gidx);
    meanpool<<<(Bz * Fz / 4) / 256, 256, 0, stream>>>(features, mean);
    gather_cvt_emb<<<(Mrows * (Ez / 4) + 255) / 256, 256, 0, stream>>>(emb_W, gidx, embg);
    permute_wih<<<(G4 * (Ez / 4)) / 256, 256, 0, stream>>>(W_ih, b_ih, b_hh, WihP, bP);
    permute_whh<<<(G4 * (Hz / 4)) / 256, 256, 0, stream>>>(W_hh, Whi);
    cvt_bf16_pad4<<<(NPAD * Hz / 4 + 255) / 256, 256, 0, stream>>>(
        fc_W, fcWb, Vz * Hz / 4, NPAD * Hz / 4);

    // init h0/c0: split-K fp32 into partial (overlaid on xg), then reduce
    initk<<<dim3(16, 2, 8), 256, 0, stream>>>(mean, Wh, Wc, partial);
    init_reduce<<<(128 * 1024) / 256, 256, 0, stream>>>(
        partial, bh, bc, haHi, haLo, c0f);

    // x-side gates (overwrites partial region — after init_reduce)
    gemm_mfma<<<dim3(G4 / 128, Mrows / 128), 256, 0, stream>>>(
        embg, WihP, bP, xg, G4, G4, Ez);

    // recurrence: one persistent kernel
    lstm_persist<<<NBLK, 256, 0, stream>>>(
        xg, Whi, haHi, haLo, hbHi, hbLo, c0f, hsb, bar);

    // output projection
    gemm_mfma<<<dim3(NPAD / 128, Mrows / 128), 256, 0, stream>>>(
        hsb, fcWb, fc_b, out, Vz, Vz, Hz);
}

// Round 5
// 626.273 us; speedup vs baseline: 3.7269x; 1.6864x over previous
//
#include <hip/hip_runtime.h>
#include <hip/hip_bf16.h>
#include <cstddef>

// Problem constants
#define Bz 128
#define Pz 196
#define Fz 2048
#define Ez 512
#define Hz 512
#define Vz 10000
#define Tz 32
#define TM 31                 // time steps
#define Mrows (Bz * TM)       // 3968
#define G4 (4 * Hz)           // 2048 gate width
#define NPAD 10112            // 79*128 padded vocab

typedef __attribute__((ext_vector_type(8))) short bf16x8;
typedef __attribute__((ext_vector_type(4))) float f32x4;

__device__ __forceinline__ void gload_lds16(const void* g, void* l) {
    __builtin_amdgcn_global_load_lds(
        (const __attribute__((address_space(1))) unsigned int*)g,
        (__attribute__((address_space(3))) unsigned int*)l, 16, 0, 0);
}
__device__ __forceinline__ ushort f2b(float x) {
    __hip_bfloat16 b = __float2bfloat16(x);
    return *reinterpret_cast<ushort*>(&b);
}
__device__ __forceinline__ float b2f(ushort u) {
    __hip_bfloat16 b = *reinterpret_cast<__hip_bfloat16*>(&u);
    return __bfloat162float(b);
}

// ---------------------------------------------------------------------------
__global__ __launch_bounds__(256) void build_gidx(const int* __restrict__ cap,
                                                  int* __restrict__ gidx) {
    int m = blockIdx.x * 256 + threadIdx.x;
    if (m < Mrows) {
        int b = m / TM;
        int t = m - b * TM;
        gidx[m] = cap[b * Tz + t];
    }
}

// ---------------------------------------------------------------------------
__global__ __launch_bounds__(256) void meanpool(const float* __restrict__ feat,
                                                float* __restrict__ mean) {
    int idx = blockIdx.x * 256 + threadIdx.x;
    int b = idx >> 9;
    int q = idx & 511;
    const float4* base = reinterpret_cast<const float4*>(feat) +
                         (size_t)b * Pz * (Fz / 4) + q;
    float4 acc = {0.f, 0.f, 0.f, 0.f};
    for (int p = 0; p < Pz; ++p) {
        float4 v = base[(size_t)p * (Fz / 4)];
        acc.x += v.x; acc.y += v.y; acc.z += v.z; acc.w += v.w;
    }
    const float s = 1.0f / (float)Pz;
    acc.x *= s; acc.y *= s; acc.z *= s; acc.w *= s;
    reinterpret_cast<float4*>(mean)[idx] = acc;
}

// ---------------------------------------------------------------------------
__global__ __launch_bounds__(256) void gather_cvt_emb(const float* __restrict__ emb,
                                                      const int* __restrict__ gidx,
                                                      ushort* __restrict__ out) {
    int idx = blockIdx.x * 256 + threadIdx.x;        // Mrows * 128
    if (idx >= Mrows * (Ez / 4)) return;
    int m = idx >> 7, kq = idx & 127;
    float4 v = reinterpret_cast<const float4*>(emb + (size_t)gidx[m] * Ez)[kq];
    ushort4 o = {f2b(v.x), f2b(v.y), f2b(v.z), f2b(v.w)};
    reinterpret_cast<ushort4*>(out + (size_t)m * Ez)[kq] = o;
}

// ---------------------------------------------------------------------------
// permute W_ih rows g*512+j -> 4j+g, convert bf16; also bP[4j+g]=b_ih+b_hh
__global__ __launch_bounds__(256) void permute_wih(const float* __restrict__ W,
                                                   const float* __restrict__ b1,
                                                   const float* __restrict__ b2,
                                                   ushort* __restrict__ WP,
                                                   float* __restrict__ bP) {
    int idx = blockIdx.x * 256 + threadIdx.x;        // 2048*128
    int o = idx >> 7, kq = idx & 127;
    int j = o >> 2, g = o & 3;
    int in = g * Hz + j;
    float4 v = reinterpret_cast<const float4*>(W + (size_t)in * Ez)[kq];
    ushort4 u = {f2b(v.x), f2b(v.y), f2b(v.z), f2b(v.w)};
    reinterpret_cast<ushort4*>(WP + (size_t)o * Ez)[kq] = u;
    if (kq == 0) bP[o] = b1[in] + b2[in];
}

// ---------------------------------------------------------------------------
// permute W_hh rows g*512+j -> 4j+g, bf16 (hi only)
__global__ __launch_bounds__(256) void permute_whh(const float* __restrict__ W,
                                                   ushort* __restrict__ Whi) {
    int idx = blockIdx.x * 256 + threadIdx.x;        // 2048*128
    int o = idx >> 7, kq = idx & 127;
    int j = o >> 2, g = o & 3;
    int in = g * Hz + j;
    float4 v = reinterpret_cast<const float4*>(W + (size_t)in * Hz)[kq];
    ushort4 h = {f2b(v.x), f2b(v.y), f2b(v.z), f2b(v.w)};
    reinterpret_cast<ushort4*>(Whi + (size_t)o * Hz)[kq] = h;
}

// ---------------------------------------------------------------------------
__global__ __launch_bounds__(256) void cvt_bf16_pad4(const float* __restrict__ s,
                                                     ushort* __restrict__ d,
                                                     int n4src, int n4dst) {
    int i = blockIdx.x * 256 + threadIdx.x;
    if (i >= n4dst) return;
    ushort4 o;
    if (i < n4src) {
        float4 v = reinterpret_cast<const float4*>(s)[i];
        o.x = f2b(v.x); o.y = f2b(v.y); o.z = f2b(v.z); o.w = f2b(v.w);
    } else {
        o.x = o.y = o.z = o.w = 0;
    }
    reinterpret_cast<ushort4*>(d)[i] = o;
}

// ---------------------------------------------------------------------------
// split-K fp32 init GEMM: partial[kz][m][n] = mean[m] . [Wh;Wc][n] over K-slice
__global__ __launch_bounds__(256) void initk(
    const float* __restrict__ mean,
    const float* __restrict__ Wh, const float* __restrict__ Wc,
    float* __restrict__ partial)
{
    __shared__ float As[64][33];
    __shared__ float Bs2[64][33];
    const int n0 = blockIdx.x * 64;    // 0..960 (1024 = Wh|Wc stacked)
    const int m0 = blockIdx.y * 64;    // 0,64
    const int kz = blockIdx.z;         // 0..7
    const int tid = threadIdx.x;
    const int tx = tid & 15, ty = tid >> 4;
    float acc[4][4] = {};

    for (int k0 = kz * 256; k0 < kz * 256 + 256; k0 += 32) {
#pragma unroll
        for (int i = 0; i < 2; ++i) {
            int e  = tid + i * 256;
            int r  = e >> 3;
            int cc = (e & 7) << 2;
            float4 va = *reinterpret_cast<const float4*>(
                mean + (size_t)(m0 + r) * Fz + k0 + cc);
            As[r][cc + 0] = va.x; As[r][cc + 1] = va.y;
            As[r][cc + 2] = va.z; As[r][cc + 3] = va.w;
            int n = n0 + r;
            const float* Brow = (n < Hz) ? (Wh + (size_t)n * Fz)
                                         : (Wc + (size_t)(n - Hz) * Fz);
            float4 vb = *reinterpret_cast<const float4*>(Brow + k0 + cc);
            Bs2[r][cc + 0] = vb.x; Bs2[r][cc + 1] = vb.y;
            Bs2[r][cc + 2] = vb.z; Bs2[r][cc + 3] = vb.w;
        }
        __syncthreads();
#pragma unroll
        for (int kk = 0; kk < 32; ++kk) {
            float a[4], bb[4];
#pragma unroll
            for (int i = 0; i < 4; ++i) a[i] = As[ty * 4 + i][kk];
#pragma unroll
            for (int j = 0; j < 4; ++j) bb[j] = Bs2[tx * 4 + j][kk];
#pragma unroll
            for (int i = 0; i < 4; ++i)
#pragma unroll
                for (int j = 0; j < 4; ++j)
                    acc[i][j] += a[i] * bb[j];
        }
        __syncthreads();
    }
#pragma unroll
    for (int i = 0; i < 4; ++i)
#pragma unroll
        for (int j = 0; j < 4; ++j)
            partial[((size_t)kz * 128 + m0 + ty * 4 + i) * 1024 + n0 + tx * 4 + j]
                = acc[i][j];
}

// ---------------------------------------------------------------------------
// reduce split-K partials; n<512 -> h0 (bf16 hi/lo), n>=512 -> c0 fp32
__global__ __launch_bounds__(256) void init_reduce(
    const float* __restrict__ partial,
    const float* __restrict__ bh, const float* __restrict__ bc,
    ushort* __restrict__ haHi, ushort* __restrict__ haLo,
    float* __restrict__ c0f)
{
    int idx = blockIdx.x * 256 + threadIdx.x;
    if (idx >= 128 * 1024) return;
    int m = idx >> 10, n = idx & 1023;
    float s = 0.f;
#pragma unroll
    for (int z = 0; z < 8; ++z)
        s += partial[((size_t)z * 128 + m) * 1024 + n];
    if (n < Hz) {
        s += bh[n];
        ushort hh = f2b(s);
        haHi[(size_t)m * Hz + n] = hh;
        haLo[(size_t)m * Hz + n] = f2b(s - b2f(hh));
    } else {
        c0f[(size_t)m * Hz + (n - Hz)] = s + bc[n - Hz];
    }
}

// ---------------------------------------------------------------------------
// bf16 MFMA GEMM (m97 structure), used for xg and fc
__global__ __launch_bounds__(256) void gemm_mfma(
    const ushort* __restrict__ A,
    const ushort* __restrict__ B,
    const float* __restrict__ bias,
    float* __restrict__ C,
    int Nb, int ldc, int K)
{
    __shared__ short Al[128 * 32];
    __shared__ short Bl[128 * 32];
    const int tid  = threadIdx.x;
    const int w    = tid >> 6;
    const int lane = tid & 63;
    const int m0 = blockIdx.y * 128;
    const int n0 = blockIdx.x * 128;
    const int wr = w >> 1, wc = w & 1;

    f32x4 acc[4][4] = {};

    const int srow = w * 32 + (lane >> 2);
    const int scol = (lane & 3) * 16;
    const char* Ag = (const char*)(A + (size_t)(m0 + srow) * K) + scol;
    const char* Bg = (const char*)(B + (size_t)(n0 + srow) * K) + scol;
    const size_t rstep = (size_t)16 * K * 2;
    short* Alb = Al + (w * 32) * 32;
    short* Blb = Bl + (w * 32) * 32;

    const int ko = (lane >> 4) * 8;
    const int fr = lane & 15;

    for (int k0 = 0; k0 < K; k0 += 32) {
        const size_t kb = (size_t)k0 * 2;
        gload_lds16(Ag + kb,         Alb);
        gload_lds16(Ag + kb + rstep, Alb + 16 * 32);
        gload_lds16(Bg + kb,         Blb);
        gload_lds16(Bg + kb + rstep, Blb + 16 * 32);
        __syncthreads();

        bf16x8 af[4], bf[4];
#pragma unroll
        for (int i = 0; i < 4; ++i)
            af[i] = *reinterpret_cast<const bf16x8*>(&Al[(wr * 64 + i * 16 + fr) * 32 + ko]);
#pragma unroll
        for (int j = 0; j < 4; ++j)
            bf[j] = *reinterpret_cast<const bf16x8*>(&Bl[(wc * 64 + j * 16 + fr) * 32 + ko]);
#pragma unroll
        for (int i = 0; i < 4; ++i)
#pragma unroll
            for (int j = 0; j < 4; ++j)
                acc[i][j] = __builtin_amdgcn_mfma_f32_16x16x32_bf16(
                    af[i], bf[j], acc[i][j], 0, 0, 0);
        __syncthreads();
    }

    const int r0 = (lane >> 4) * 4;
#pragma unroll
    for (int i = 0; i < 4; ++i) {
        int row = m0 + wr * 64 + i * 16 + r0;
#pragma unroll
        for (int j = 0; j < 4; ++j) {
            int col = n0 + wc * 64 + j * 16 + fr;
            if (col < Nb) {
                float bb = bias ? bias[col] : 0.f;
#pragma unroll
                for (int r = 0; r < 4; ++r)
                    C[(size_t)(row + r) * ldc + col] = acc[i][j][r] + bb;
            }
        }
    }
}

// ---------------------------------------------------------------------------
// One LSTM step, all-direct-to-VGPR MFMA (no LDS staging, no K-loop syncs).
// Grid 128 blocks x 256 thr. Block owns 16 permuted gate cols (4 h-indices).
// Wave w: M rows w*32..w*32+31, full 16 cols. Operands L2-resident.
__global__ __launch_bounds__(256) void lstm_step2(
    const float* __restrict__ xg,
    const ushort* __restrict__ Whi,
    const ushort* __restrict__ Ah,  const ushort* __restrict__ Alo,
    ushort* __restrict__ Oh, ushort* __restrict__ Ol,
    float* __restrict__ cst, ushort* __restrict__ hsb, int t)
{
    __shared__ float Cl[128][17];

    const int tid  = threadIdx.x;
    const int w    = tid >> 6;
    const int lane = tid & 63;
    const int fr   = lane & 15;
    const int hi4  = lane >> 4;           // 0..3
    const int n0   = blockIdx.x * 16;
    const int j0   = n0 >> 2;             // 4 h-indices per block
    const int m0w  = w * 32;

    f32x4 acc[2] = {};

    const ushort* Bp  = Whi + (size_t)(n0 + fr) * Hz;
    const ushort* Ap0 = Ah  + (size_t)(m0w + fr) * Hz;
    const ushort* Ap1 = Ah  + (size_t)(m0w + 16 + fr) * Hz;
    const ushort* Lp0 = Alo + (size_t)(m0w + fr) * Hz;
    const ushort* Lp1 = Alo + (size_t)(m0w + 16 + fr) * Hz;

#pragma unroll
    for (int kc = 0; kc < 16; ++kc) {
        const size_t koff = (size_t)kc * 32 + hi4 * 8;
        bf16x8 bv  = *reinterpret_cast<const bf16x8*>(Bp  + koff);
        bf16x8 ah0 = *reinterpret_cast<const bf16x8*>(Ap0 + koff);
        bf16x8 ah1 = *reinterpret_cast<const bf16x8*>(Ap1 + koff);
        bf16x8 al0 = *reinterpret_cast<const bf16x8*>(Lp0 + koff);
        bf16x8 al1 = *reinterpret_cast<const bf16x8*>(Lp1 + koff);
        acc[0] = __builtin_amdgcn_mfma_f32_16x16x32_bf16(ah0, bv, acc[0], 0, 0, 0);
        acc[1] = __builtin_amdgcn_mfma_f32_16x16x32_bf16(ah1, bv, acc[1], 0, 0, 0);
        acc[0] = __builtin_amdgcn_mfma_f32_16x16x32_bf16(al0, bv, acc[0], 0, 0, 0);
        acc[1] = __builtin_amdgcn_mfma_f32_16x16x32_bf16(al1, bv, acc[1], 0, 0, 0);
    }

    // regroup gates into Cl[m][col]; C/D layout: col=fr, row=hi4*4+r
#pragma unroll
    for (int i = 0; i < 2; ++i)
#pragma unroll
        for (int r = 0; r < 4; ++r)
            Cl[m0w + i * 16 + hi4 * 4 + r][fr] = acc[i][r];
    __syncthreads();

    // elementwise: 256 threads, each owns (m = tid>>1, 2 h-indices)
    {
        const int m  = tid >> 1;
        const int hp = (tid & 1) * 2;
        const float* xr = xg + ((size_t)m * TM + t) * G4 + n0 + 4 * hp;
        float4 x0 = *reinterpret_cast<const float4*>(xr);
        float4 x1 = *reinterpret_cast<const float4*>(xr + 4);
        float2 cc = *reinterpret_cast<const float2*>(cst + (size_t)m * Hz + j0 + hp);

        float gi0 = Cl[m][4 * hp + 0] + x0.x;
        float gf0 = Cl[m][4 * hp + 1] + x0.y;
        float gg0 = Cl[m][4 * hp + 2] + x0.z;
        float go0 = Cl[m][4 * hp + 3] + x0.w;
        float gi1 = Cl[m][4 * hp + 4] + x1.x;
        float gf1 = Cl[m][4 * hp + 5] + x1.y;
        float gg1 = Cl[m][4 * hp + 6] + x1.z;
        float go1 = Cl[m][4 * hp + 7] + x1.w;

        float i0 = 1.f / (1.f + expf(-gi0));
        float f0 = 1.f / (1.f + expf(-gf0));
        float g0 = tanhf(gg0);
        float o0 = 1.f / (1.f + expf(-go0));
        float i1 = 1.f / (1.f + expf(-gi1));
        float f1 = 1.f / (1.f + expf(-gf1));
        float g1 = tanhf(gg1);
        float o1 = 1.f / (1.f + expf(-go1));

        float cn0 = f0 * cc.x + i0 * g0;
        float cn1 = f1 * cc.y + i1 * g1;
        float h0v = o0 * tanhf(cn0);
        float h1v = o1 * tanhf(cn1);

        float2 cno = {cn0, cn1};
        *reinterpret_cast<float2*>(cst + (size_t)m * Hz + j0 + hp) = cno;

        ushort hh0 = f2b(h0v), hh1 = f2b(h1v);
        ushort hl0 = f2b(h0v - b2f(hh0)), hl1 = f2b(h1v - b2f(hh1));
        uint uh = (uint)hh0 | ((uint)hh1 << 16);
        uint ul = (uint)hl0 | ((uint)hl1 << 16);
        *reinterpret_cast<uint*>(Oh + (size_t)m * Hz + j0 + hp) = uh;
        *reinterpret_cast<uint*>(Ol + (size_t)m * Hz + j0 + hp) = ul;
        *reinterpret_cast<uint*>(hsb + ((size_t)m * TM + t) * Hz + j0 + hp) = uh;
    }
}

// ---------------------------------------------------------------------------
extern "C" void kernel_launch(void* const* d_in, const int* in_sizes, int n_in,
                              void* d_out, int out_size, void* d_ws, size_t ws_size,
                              hipStream_t stream) {
    const float* features = (const float*)d_in[0];
    const int*   captions = (const int*)d_in[1];
    const float* emb_W    = (const float*)d_in[2];
    const float* W_ih     = (const float*)d_in[3];
    const float* W_hh     = (const float*)d_in[4];
    const float* b_ih     = (const float*)d_in[5];
    const float* b_hh     = (const float*)d_in[6];
    const float* Wh       = (const float*)d_in[7];
    const float* bh       = (const float*)d_in[8];
    const float* Wc       = (const float*)d_in[9];
    const float* bc       = (const float*)d_in[10];
    const float* fc_W     = (const float*)d_in[11];
    const float* fc_b     = (const float*)d_in[12];
    float* out = (float*)d_out;

    // workspace carve-up
    float* w    = (float*)d_ws;
    float* mean = w;                            // 262144 f
    float* xg   = mean + Bz * Fz;               // 8,126,464 f (partial overlaid)
    float* partial = xg;                        // [8][128][1024] f, used pre-xg
    float* c0f  = xg + (size_t)Mrows * G4;      // 65536 f
    float* bP   = c0f + Bz * Hz;                // 2048 f
    int*  gidx  = (int*)(bP + G4);              // 3968 i
    ushort* embg = (ushort*)(gidx + Mrows + 64);// 3968*512
    ushort* WihP = embg + (size_t)Mrows * Ez;   // 2048*512
    ushort* Whi  = WihP + (size_t)G4 * Ez;      // 2048*512
    ushort* fcWb = Whi + (size_t)G4 * Hz;       // 10112*512
    ushort* hsb  = fcWb + (size_t)NPAD * Hz;    // 3968*512
    ushort* haHi = hsb + (size_t)Mrows * Hz;    // 128*512 each below
    ushort* haLo = haHi + Bz * Hz;
    ushort* hbHi = haLo + Bz * Hz;
    ushort* hbLo = hbHi + Bz * Hz;

    build_gidx<<<(Mrows + 255) / 256, 256, 0, stream>>>(captions, gidx);
    meanpool<<<(Bz * Fz / 4) / 256, 256, 0, stream>>>(features, mean);
    gather_cvt_emb<<<(Mrows * (Ez / 4) + 255) / 256, 256, 0, stream>>>(emb_W, gidx, embg);
    permute_wih<<<(G4 * (Ez / 4)) / 256, 256, 0, stream>>>(W_ih, b_ih, b_hh, WihP, bP);
    permute_whh<<<(G4 * (Hz / 4)) / 256, 256, 0, stream>>>(W_hh, Whi);
    cvt_bf16_pad4<<<(NPAD * Hz / 4 + 255) / 256, 256, 0, stream>>>(
        fc_W, fcWb, Vz * Hz / 4, NPAD * Hz / 4);

    // init h0/c0: split-K fp32 into partial (overlaid on xg), then reduce
    initk<<<dim3(16, 2, 8), 256, 0, stream>>>(mean, Wh, Wc, partial);
    init_reduce<<<(128 * 1024) / 256, 256, 0, stream>>>(
        partial, bh, bc, haHi, haLo, c0f);

    // x-side gates (overwrites partial region — after init_reduce)
    gemm_mfma<<<dim3(G4 / 128, Mrows / 128), 256, 0, stream>>>(
        embg, WihP, bP, xg, G4, G4, Ez);

    // recurrence: 31 per-step launches (kernel-boundary sync)
    for (int t = 0; t < TM; ++t) {
        const ushort* ih = (t & 1) ? hbHi : haHi;
        const ushort* il = (t & 1) ? hbLo : haLo;
        ushort* oh = (t & 1) ? haHi : hbHi;
        ushort* ol = (t & 1) ? haLo : hbLo;
        lstm_step2<<<G4 / 16, 256, 0, stream>>>(
            xg, Whi, ih, il, oh, ol, c0f, hsb, t);
    }

    // output projection
    gemm_mfma<<<dim3(NPAD / 128, Mrows / 128), 256, 0, stream>>>(
        hsb, fcWb, fc_b, out, Vz, Vz, Hz);
}

// Round 6
// 484.152 us; speedup vs baseline: 4.8209x; 1.2935x over previous
//
#include <hip/hip_runtime.h>
#include <hip/hip_bf16.h>
#include <cstddef>

// Problem constants
#define Bz 128
#define Pz 196
#define Fz 2048
#define Ez 512
#define Hz 512
#define Vz 10000
#define Tz 32
#define TM 31                 // time steps
#define Mrows (Bz * TM)       // 3968
#define G4 (4 * Hz)           // 2048 gate width
#define NPAD 10112            // 79*128 padded vocab

typedef __attribute__((ext_vector_type(8))) short bf16x8;
typedef __attribute__((ext_vector_type(4))) float f32x4;

__device__ __forceinline__ void gload_lds16(const void* g, void* l) {
    __builtin_amdgcn_global_load_lds(
        (const __attribute__((address_space(1))) unsigned int*)g,
        (__attribute__((address_space(3))) unsigned int*)l, 16, 0, 0);
}
__device__ __forceinline__ ushort f2b(float x) {
    __hip_bfloat16 b = __float2bfloat16(x);
    return *reinterpret_cast<ushort*>(&b);
}
__device__ __forceinline__ float b2f(ushort u) {
    __hip_bfloat16 b = *reinterpret_cast<__hip_bfloat16*>(&u);
    return __bfloat162float(b);
}

// ---------------------------------------------------------------------------
__global__ __launch_bounds__(256) void meanpool(const float* __restrict__ feat,
                                                float* __restrict__ mean) {
    int idx = blockIdx.x * 256 + threadIdx.x;
    int b = idx >> 9;
    int q = idx & 511;
    const float4* base = reinterpret_cast<const float4*>(feat) +
                         (size_t)b * Pz * (Fz / 4) + q;
    float4 acc = {0.f, 0.f, 0.f, 0.f};
    for (int p = 0; p < Pz; ++p) {
        float4 v = base[(size_t)p * (Fz / 4)];
        acc.x += v.x; acc.y += v.y; acc.z += v.z; acc.w += v.w;
    }
    const float s = 1.0f / (float)Pz;
    acc.x *= s; acc.y *= s; acc.z *= s; acc.w *= s;
    reinterpret_cast<float4*>(mean)[idx] = acc;
}

// ---------------------------------------------------------------------------
// gather caption embeddings + cvt bf16 (index computed inline)
__global__ __launch_bounds__(256) void gather_cvt_emb(const float* __restrict__ emb,
                                                      const int* __restrict__ cap,
                                                      ushort* __restrict__ out) {
    int idx = blockIdx.x * 256 + threadIdx.x;        // Mrows * 128
    if (idx >= Mrows * (Ez / 4)) return;
    int m = idx >> 7, kq = idx & 127;
    int b = m / TM;
    int t = m - b * TM;
    int row = cap[b * Tz + t];
    float4 v = reinterpret_cast<const float4*>(emb + (size_t)row * Ez)[kq];
    ushort4 o = {f2b(v.x), f2b(v.y), f2b(v.z), f2b(v.w)};
    reinterpret_cast<ushort4*>(out + (size_t)m * Ez)[kq] = o;
}

// ---------------------------------------------------------------------------
// permute W_ih rows g*512+j -> 4j+g, convert bf16; also bP[4j+g]=b_ih+b_hh
__global__ __launch_bounds__(256) void permute_wih(const float* __restrict__ W,
                                                   const float* __restrict__ b1,
                                                   const float* __restrict__ b2,
                                                   ushort* __restrict__ WP,
                                                   float* __restrict__ bP) {
    int idx = blockIdx.x * 256 + threadIdx.x;        // 2048*128
    int o = idx >> 7, kq = idx & 127;
    int j = o >> 2, g = o & 3;
    int in = g * Hz + j;
    float4 v = reinterpret_cast<const float4*>(W + (size_t)in * Ez)[kq];
    ushort4 u = {f2b(v.x), f2b(v.y), f2b(v.z), f2b(v.w)};
    reinterpret_cast<ushort4*>(WP + (size_t)o * Ez)[kq] = u;
    if (kq == 0) bP[o] = b1[in] + b2[in];
}

// ---------------------------------------------------------------------------
// permute W_hh rows g*512+j -> 4j+g, bf16 (hi only)
__global__ __launch_bounds__(256) void permute_whh(const float* __restrict__ W,
                                                   ushort* __restrict__ Whi) {
    int idx = blockIdx.x * 256 + threadIdx.x;        // 2048*128
    int o = idx >> 7, kq = idx & 127;
    int j = o >> 2, g = o & 3;
    int in = g * Hz + j;
    float4 v = reinterpret_cast<const float4*>(W + (size_t)in * Hz)[kq];
    ushort4 h = {f2b(v.x), f2b(v.y), f2b(v.z), f2b(v.w)};
    reinterpret_cast<ushort4*>(Whi + (size_t)o * Hz)[kq] = h;
}

// ---------------------------------------------------------------------------
__global__ __launch_bounds__(256) void cvt_bf16_pad4(const float* __restrict__ s,
                                                     ushort* __restrict__ d,
                                                     int n4src, int n4dst) {
    int i = blockIdx.x * 256 + threadIdx.x;
    if (i >= n4dst) return;
    ushort4 o;
    if (i < n4src) {
        float4 v = reinterpret_cast<const float4*>(s)[i];
        o.x = f2b(v.x); o.y = f2b(v.y); o.z = f2b(v.z); o.w = f2b(v.w);
    } else {
        o.x = o.y = o.z = o.w = 0;
    }
    reinterpret_cast<ushort4*>(d)[i] = o;
}

// ---------------------------------------------------------------------------
// split-K fp32 init GEMM: partial[kz][m][n] = mean[m] . [Wh;Wc][n] over K-slice
__global__ __launch_bounds__(256) void initk(
    const float* __restrict__ mean,
    const float* __restrict__ Wh, const float* __restrict__ Wc,
    float* __restrict__ partial)
{
    __shared__ float As[64][33];
    __shared__ float Bs2[64][33];
    const int n0 = blockIdx.x * 64;    // 0..960 (1024 = Wh|Wc stacked)
    const int m0 = blockIdx.y * 64;    // 0,64
    const int kz = blockIdx.z;         // 0..7
    const int tid = threadIdx.x;
    const int tx = tid & 15, ty = tid >> 4;
    float acc[4][4] = {};

    for (int k0 = kz * 256; k0 < kz * 256 + 256; k0 += 32) {
#pragma unroll
        for (int i = 0; i < 2; ++i) {
            int e  = tid + i * 256;
            int r  = e >> 3;
            int cc = (e & 7) << 2;
            float4 va = *reinterpret_cast<const float4*>(
                mean + (size_t)(m0 + r) * Fz + k0 + cc);
            As[r][cc + 0] = va.x; As[r][cc + 1] = va.y;
            As[r][cc + 2] = va.z; As[r][cc + 3] = va.w;
            int n = n0 + r;
            const float* Brow = (n < Hz) ? (Wh + (size_t)n * Fz)
                                         : (Wc + (size_t)(n - Hz) * Fz);
            float4 vb = *reinterpret_cast<const float4*>(Brow + k0 + cc);
            Bs2[r][cc + 0] = vb.x; Bs2[r][cc + 1] = vb.y;
            Bs2[r][cc + 2] = vb.z; Bs2[r][cc + 3] = vb.w;
        }
        __syncthreads();
#pragma unroll
        for (int kk = 0; kk < 32; ++kk) {
            float a[4], bb[4];
#pragma unroll
            for (int i = 0; i < 4; ++i) a[i] = As[ty * 4 + i][kk];
#pragma unroll
            for (int j = 0; j < 4; ++j) bb[j] = Bs2[tx * 4 + j][kk];
#pragma unroll
            for (int i = 0; i < 4; ++i)
#pragma unroll
                for (int j = 0; j < 4; ++j)
                    acc[i][j] += a[i] * bb[j];
        }
        __syncthreads();
    }
#pragma unroll
    for (int i = 0; i < 4; ++i)
#pragma unroll
        for (int j = 0; j < 4; ++j)
            partial[((size_t)kz * 128 + m0 + ty * 4 + i) * 1024 + n0 + tx * 4 + j]
                = acc[i][j];
}

// ---------------------------------------------------------------------------
// reduce split-K partials; n<512 -> h0 (bf16 hi/lo), n>=512 -> c0 fp32
__global__ __launch_bounds__(256) void init_reduce(
    const float* __restrict__ partial,
    const float* __restrict__ bh, const float* __restrict__ bc,
    ushort* __restrict__ haHi, ushort* __restrict__ haLo,
    float* __restrict__ c0f)
{
    int idx = blockIdx.x * 256 + threadIdx.x;
    if (idx >= 128 * 1024) return;
    int m = idx >> 10, n = idx & 1023;
    float s = 0.f;
#pragma unroll
    for (int z = 0; z < 8; ++z)
        s += partial[((size_t)z * 128 + m) * 1024 + n];
    if (n < Hz) {
        s += bh[n];
        ushort hh = f2b(s);
        haHi[(size_t)m * Hz + n] = hh;
        haLo[(size_t)m * Hz + n] = f2b(s - b2f(hh));
    } else {
        c0f[(size_t)m * Hz + (n - Hz)] = s + bc[n - Hz];
    }
}

// ---------------------------------------------------------------------------
// bf16 MFMA GEMM (m97 structure) + T1 bijective XCD swizzle (m204)
__global__ __launch_bounds__(256) void gemm_mfma(
    const ushort* __restrict__ A,
    const ushort* __restrict__ B,
    const float* __restrict__ bias,
    float* __restrict__ C,
    int Nb, int ldc, int K)
{
    __shared__ short Al[128 * 32];
    __shared__ short Bl[128 * 32];
    const int tid  = threadIdx.x;
    const int w    = tid >> 6;
    const int lane = tid & 63;

    // bijective XCD swizzle: contiguous grid chunk per XCD
    const int nwg  = gridDim.x * gridDim.y;
    int orig = blockIdx.y * gridDim.x + blockIdx.x;
    int q = nwg >> 3, r = nwg & 7;
    int xcd = orig & 7, local = orig >> 3;
    int wgid = (xcd < r ? xcd * (q + 1) : r * (q + 1) + (xcd - r) * q) + local;
    const int m0 = (wgid / gridDim.x) * 128;
    const int n0 = (wgid % gridDim.x) * 128;
    const int wr = w >> 1, wc = w & 1;

    f32x4 acc[4][4] = {};

    const int srow = w * 32 + (lane >> 2);
    const int scol = (lane & 3) * 16;
    const char* Ag = (const char*)(A + (size_t)(m0 + srow) * K) + scol;
    const char* Bg = (const char*)(B + (size_t)(n0 + srow) * K) + scol;
    const size_t rstep = (size_t)16 * K * 2;
    short* Alb = Al + (w * 32) * 32;
    short* Blb = Bl + (w * 32) * 32;

    const int ko = (lane >> 4) * 8;
    const int fr = lane & 15;

    for (int k0 = 0; k0 < K; k0 += 32) {
        const size_t kb = (size_t)k0 * 2;
        gload_lds16(Ag + kb,         Alb);
        gload_lds16(Ag + kb + rstep, Alb + 16 * 32);
        gload_lds16(Bg + kb,         Blb);
        gload_lds16(Bg + kb + rstep, Blb + 16 * 32);
        __syncthreads();

        bf16x8 af[4], bf[4];
#pragma unroll
        for (int i = 0; i < 4; ++i)
            af[i] = *reinterpret_cast<const bf16x8*>(&Al[(wr * 64 + i * 16 + fr) * 32 + ko]);
#pragma unroll
        for (int j = 0; j < 4; ++j)
            bf[j] = *reinterpret_cast<const bf16x8*>(&Bl[(wc * 64 + j * 16 + fr) * 32 + ko]);
#pragma unroll
        for (int i = 0; i < 4; ++i)
#pragma unroll
            for (int j = 0; j < 4; ++j)
                acc[i][j] = __builtin_amdgcn_mfma_f32_16x16x32_bf16(
                    af[i], bf[j], acc[i][j], 0, 0, 0);
        __syncthreads();
    }

    const int r0 = (lane >> 4) * 4;
#pragma unroll
    for (int i = 0; i < 4; ++i) {
        int row = m0 + wr * 64 + i * 16 + r0;
#pragma unroll
        for (int j = 0; j < 4; ++j) {
            int col = n0 + wc * 64 + j * 16 + fr;
            if (col < Nb) {
                float bb = bias ? bias[col] : 0.f;
#pragma unroll
                for (int rr = 0; rr < 4; ++rr)
                    C[(size_t)(row + rr) * ldc + col] = acc[i][j][rr] + bb;
            }
        }
    }
}

// ---------------------------------------------------------------------------
// One LSTM step, direct-to-VGPR MFMA, grid (128 col-groups, 2 m-halves),
// 128 thr = 2 waves -> 256 blocks, one per CU.
__global__ __launch_bounds__(128) void lstm_step2(
    const float* __restrict__ xg,
    const ushort* __restrict__ Whi,
    const ushort* __restrict__ Ah,  const ushort* __restrict__ Alo,
    ushort* __restrict__ Oh, ushort* __restrict__ Ol,
    float* __restrict__ cst, ushort* __restrict__ hsb, int t)
{
    __shared__ float Cl[64][17];

    const int tid  = threadIdx.x;
    const int w    = tid >> 6;            // 0..1
    const int lane = tid & 63;
    const int fr   = lane & 15;
    const int hi4  = lane >> 4;           // 0..3
    const int n0   = blockIdx.x * 16;
    const int j0   = n0 >> 2;             // 4 h-indices per block
    const int mb   = blockIdx.y * 64;     // m half
    const int m0w  = mb + w * 32;

    f32x4 acc[2] = {};

    const ushort* Bp  = Whi + (size_t)(n0 + fr) * Hz;
    const ushort* Ap0 = Ah  + (size_t)(m0w + fr) * Hz;
    const ushort* Ap1 = Ah  + (size_t)(m0w + 16 + fr) * Hz;
    const ushort* Lp0 = Alo + (size_t)(m0w + fr) * Hz;
    const ushort* Lp1 = Alo + (size_t)(m0w + 16 + fr) * Hz;

#pragma unroll
    for (int kc = 0; kc < 16; ++kc) {
        const size_t koff = (size_t)kc * 32 + hi4 * 8;
        bf16x8 bv  = *reinterpret_cast<const bf16x8*>(Bp  + koff);
        bf16x8 ah0 = *reinterpret_cast<const bf16x8*>(Ap0 + koff);
        bf16x8 ah1 = *reinterpret_cast<const bf16x8*>(Ap1 + koff);
        bf16x8 al0 = *reinterpret_cast<const bf16x8*>(Lp0 + koff);
        bf16x8 al1 = *reinterpret_cast<const bf16x8*>(Lp1 + koff);
        acc[0] = __builtin_amdgcn_mfma_f32_16x16x32_bf16(ah0, bv, acc[0], 0, 0, 0);
        acc[1] = __builtin_amdgcn_mfma_f32_16x16x32_bf16(ah1, bv, acc[1], 0, 0, 0);
        acc[0] = __builtin_amdgcn_mfma_f32_16x16x32_bf16(al0, bv, acc[0], 0, 0, 0);
        acc[1] = __builtin_amdgcn_mfma_f32_16x16x32_bf16(al1, bv, acc[1], 0, 0, 0);
    }

    // regroup gates into Cl[local m][col]; C/D layout: col=fr, row=hi4*4+r
#pragma unroll
    for (int i = 0; i < 2; ++i)
#pragma unroll
        for (int r = 0; r < 4; ++r)
            Cl[w * 32 + i * 16 + hi4 * 4 + r][fr] = acc[i][r];
    __syncthreads();

    // elementwise: 128 threads, each owns (local m = tid>>1, 2 h-indices)
    {
        const int lm = tid >> 1;
        const int m  = mb + lm;
        const int hp = (tid & 1) * 2;
        const float* xr = xg + ((size_t)m * TM + t) * G4 + n0 + 4 * hp;
        float4 x0 = *reinterpret_cast<const float4*>(xr);
        float4 x1 = *reinterpret_cast<const float4*>(xr + 4);
        float2 cc = *reinterpret_cast<const float2*>(cst + (size_t)m * Hz + j0 + hp);

        float gi0 = Cl[lm][4 * hp + 0] + x0.x;
        float gf0 = Cl[lm][4 * hp + 1] + x0.y;
        float gg0 = Cl[lm][4 * hp + 2] + x0.z;
        float go0 = Cl[lm][4 * hp + 3] + x0.w;
        float gi1 = Cl[lm][4 * hp + 4] + x1.x;
        float gf1 = Cl[lm][4 * hp + 5] + x1.y;
        float gg1 = Cl[lm][4 * hp + 6] + x1.z;
        float go1 = Cl[lm][4 * hp + 7] + x1.w;

        float i0 = 1.f / (1.f + expf(-gi0));
        float f0 = 1.f / (1.f + expf(-gf0));
        float g0 = tanhf(gg0);
        float o0 = 1.f / (1.f + expf(-go0));
        float i1 = 1.f / (1.f + expf(-gi1));
        float f1 = 1.f / (1.f + expf(-gf1));
        float g1 = tanhf(gg1);
        float o1 = 1.f / (1.f + expf(-go1));

        float cn0 = f0 * cc.x + i0 * g0;
        float cn1 = f1 * cc.y + i1 * g1;
        float h0v = o0 * tanhf(cn0);
        float h1v = o1 * tanhf(cn1);

        float2 cno = {cn0, cn1};
        *reinterpret_cast<float2*>(cst + (size_t)m * Hz + j0 + hp) = cno;

        ushort hh0 = f2b(h0v), hh1 = f2b(h1v);
        ushort hl0 = f2b(h0v - b2f(hh0)), hl1 = f2b(h1v - b2f(hh1));
        uint uh = (uint)hh0 | ((uint)hh1 << 16);
        uint ul = (uint)hl0 | ((uint)hl1 << 16);
        *reinterpret_cast<uint*>(Oh + (size_t)m * Hz + j0 + hp) = uh;
        *reinterpret_cast<uint*>(Ol + (size_t)m * Hz + j0 + hp) = ul;
        *reinterpret_cast<uint*>(hsb + ((size_t)m * TM + t) * Hz + j0 + hp) = uh;
    }
}

// ---------------------------------------------------------------------------
extern "C" void kernel_launch(void* const* d_in, const int* in_sizes, int n_in,
                              void* d_out, int out_size, void* d_ws, size_t ws_size,
                              hipStream_t stream) {
    const float* features = (const float*)d_in[0];
    const int*   captions = (const int*)d_in[1];
    const float* emb_W    = (const float*)d_in[2];
    const float* W_ih     = (const float*)d_in[3];
    const float* W_hh     = (const float*)d_in[4];
    const float* b_ih     = (const float*)d_in[5];
    const float* b_hh     = (const float*)d_in[6];
    const float* Wh       = (const float*)d_in[7];
    const float* bh       = (const float*)d_in[8];
    const float* Wc       = (const float*)d_in[9];
    const float* bc       = (const float*)d_in[10];
    const float* fc_W     = (const float*)d_in[11];
    const float* fc_b     = (const float*)d_in[12];
    float* out = (float*)d_out;

    // workspace carve-up
    float* w    = (float*)d_ws;
    float* mean = w;                            // 262144 f
    float* xg   = mean + Bz * Fz;               // 8,126,464 f (partial overlaid)
    float* partial = xg;                        // [8][128][1024] f, used pre-xg
    float* c0f  = xg + (size_t)Mrows * G4;      // 65536 f
    float* bP   = c0f + Bz * Hz;                // 2048 f
    ushort* embg = (ushort*)(bP + G4);          // 3968*512
    ushort* WihP = embg + (size_t)Mrows * Ez;   // 2048*512
    ushort* Whi  = WihP + (size_t)G4 * Ez;      // 2048*512
    ushort* fcWb = Whi + (size_t)G4 * Hz;       // 10112*512
    ushort* hsb  = fcWb + (size_t)NPAD * Hz;    // 3968*512
    ushort* haHi = hsb + (size_t)Mrows * Hz;    // 128*512 each below
    ushort* haLo = haHi + Bz * Hz;
    ushort* hbHi = haLo + Bz * Hz;
    ushort* hbLo = hbHi + Bz * Hz;

    meanpool<<<(Bz * Fz / 4) / 256, 256, 0, stream>>>(features, mean);
    gather_cvt_emb<<<(Mrows * (Ez / 4) + 255) / 256, 256, 0, stream>>>(emb_W, captions, embg);
    permute_wih<<<(G4 * (Ez / 4)) / 256, 256, 0, stream>>>(W_ih, b_ih, b_hh, WihP, bP);
    permute_whh<<<(G4 * (Hz / 4)) / 256, 256, 0, stream>>>(W_hh, Whi);
    cvt_bf16_pad4<<<(NPAD * Hz / 4 + 255) / 256, 256, 0, stream>>>(
        fc_W, fcWb, Vz * Hz / 4, NPAD * Hz / 4);

    // init h0/c0: split-K fp32 into partial (overlaid on xg), then reduce
    initk<<<dim3(16, 2, 8), 256, 0, stream>>>(mean, Wh, Wc, partial);
    init_reduce<<<(128 * 1024) / 256, 256, 0, stream>>>(
        partial, bh, bc, haHi, haLo, c0f);

    // x-side gates (overwrites partial region — after init_reduce)
    gemm_mfma<<<dim3(G4 / 128, Mrows / 128), 256, 0, stream>>>(
        embg, WihP, bP, xg, G4, G4, Ez);

    // recurrence: 31 per-step launches, all 256 CUs active
    for (int t = 0; t < TM; ++t) {
        const ushort* ih = (t & 1) ? hbHi : haHi;
        const ushort* il = (t & 1) ? hbLo : haLo;
        ushort* oh = (t & 1) ? haHi : hbHi;
        ushort* ol = (t & 1) ? haLo : hbLo;
        lstm_step2<<<dim3(G4 / 16, 2), 128, 0, stream>>>(
            xg, Whi, ih, il, oh, ol, c0f, hsb, t);
    }

    // output projection
    gemm_mfma<<<dim3(NPAD / 128, Mrows / 128), 256, 0, stream>>>(
        hsb, fcWb, fc_b, out, Vz, Vz, Hz);
}

// Round 7
// 482.093 us; speedup vs baseline: 4.8415x; 1.0043x over previous
//
#include <hip/hip_runtime.h>
#include <hip/hip_bf16.h>
#include <cstddef>

// Problem constants
#define Bz 128
#define Pz 196
#define Fz 2048
#define Ez 512
#define Hz 512
#define Vz 10000
#define Tz 32
#define TM 31                 // time steps
#define Mrows (Bz * TM)       // 3968
#define G4 (4 * Hz)           // 2048 gate width
#define NPAD 10112            // 79*128 padded vocab

typedef __attribute__((ext_vector_type(8))) short bf16x8;
typedef __attribute__((ext_vector_type(4))) float f32x4;

__device__ __forceinline__ void gload_lds16(const void* g, void* l) {
    __builtin_amdgcn_global_load_lds(
        (const __attribute__((address_space(1))) unsigned int*)g,
        (__attribute__((address_space(3))) unsigned int*)l, 16, 0, 0);
}
__device__ __forceinline__ ushort f2b(float x) {
    __hip_bfloat16 b = __float2bfloat16(x);
    return *reinterpret_cast<ushort*>(&b);
}
__device__ __forceinline__ float b2f(ushort u) {
    __hip_bfloat16 b = *reinterpret_cast<__hip_bfloat16*>(&u);
    return __bfloat162float(b);
}

// ---------------------------------------------------------------------------
__global__ __launch_bounds__(256) void meanpool(const float* __restrict__ feat,
                                                float* __restrict__ mean) {
    int idx = blockIdx.x * 256 + threadIdx.x;
    int b = idx >> 9;
    int q = idx & 511;
    const float4* base = reinterpret_cast<const float4*>(feat) +
                         (size_t)b * Pz * (Fz / 4) + q;
    float4 acc = {0.f, 0.f, 0.f, 0.f};
    for (int p = 0; p < Pz; ++p) {
        float4 v = base[(size_t)p * (Fz / 4)];
        acc.x += v.x; acc.y += v.y; acc.z += v.z; acc.w += v.w;
    }
    const float s = 1.0f / (float)Pz;
    acc.x *= s; acc.y *= s; acc.z *= s; acc.w *= s;
    reinterpret_cast<float4*>(mean)[idx] = acc;
}

// ---------------------------------------------------------------------------
// gather caption embeddings + cvt bf16 (index computed inline)
__global__ __launch_bounds__(256) void gather_cvt_emb(const float* __restrict__ emb,
                                                      const int* __restrict__ cap,
                                                      ushort* __restrict__ out) {
    int idx = blockIdx.x * 256 + threadIdx.x;        // Mrows * 128
    if (idx >= Mrows * (Ez / 4)) return;
    int m = idx >> 7, kq = idx & 127;
    int b = m / TM;
    int t = m - b * TM;
    int row = cap[b * Tz + t];
    float4 v = reinterpret_cast<const float4*>(emb + (size_t)row * Ez)[kq];
    ushort4 o = {f2b(v.x), f2b(v.y), f2b(v.z), f2b(v.w)};
    reinterpret_cast<ushort4*>(out + (size_t)m * Ez)[kq] = o;
}

// ---------------------------------------------------------------------------
// permute W_ih rows g*512+j -> 4j+g, convert bf16; also bP[4j+g]=b_ih+b_hh
__global__ __launch_bounds__(256) void permute_wih(const float* __restrict__ W,
                                                   const float* __restrict__ b1,
                                                   const float* __restrict__ b2,
                                                   ushort* __restrict__ WP,
                                                   float* __restrict__ bP) {
    int idx = blockIdx.x * 256 + threadIdx.x;        // 2048*128
    int o = idx >> 7, kq = idx & 127;
    int j = o >> 2, g = o & 3;
    int in = g * Hz + j;
    float4 v = reinterpret_cast<const float4*>(W + (size_t)in * Ez)[kq];
    ushort4 u = {f2b(v.x), f2b(v.y), f2b(v.z), f2b(v.w)};
    reinterpret_cast<ushort4*>(WP + (size_t)o * Ez)[kq] = u;
    if (kq == 0) bP[o] = b1[in] + b2[in];
}

// ---------------------------------------------------------------------------
// permute W_hh rows g*512+j -> 4j+g, bf16 (hi only)
__global__ __launch_bounds__(256) void permute_whh(const float* __restrict__ W,
                                                   ushort* __restrict__ Whi) {
    int idx = blockIdx.x * 256 + threadIdx.x;        // 2048*128
    int o = idx >> 7, kq = idx & 127;
    int j = o >> 2, g = o & 3;
    int in = g * Hz + j;
    float4 v = reinterpret_cast<const float4*>(W + (size_t)in * Hz)[kq];
    ushort4 h = {f2b(v.x), f2b(v.y), f2b(v.z), f2b(v.w)};
    reinterpret_cast<ushort4*>(Whi + (size_t)o * Hz)[kq] = h;
}

// ---------------------------------------------------------------------------
__global__ __launch_bounds__(256) void cvt_bf16_pad4(const float* __restrict__ s,
                                                     ushort* __restrict__ d,
                                                     int n4src, int n4dst) {
    int i = blockIdx.x * 256 + threadIdx.x;
    if (i >= n4dst) return;
    ushort4 o;
    if (i < n4src) {
        float4 v = reinterpret_cast<const float4*>(s)[i];
        o.x = f2b(v.x); o.y = f2b(v.y); o.z = f2b(v.z); o.w = f2b(v.w);
    } else {
        o.x = o.y = o.z = o.w = 0;
    }
    reinterpret_cast<ushort4*>(d)[i] = o;
}

// ---------------------------------------------------------------------------
// split-K fp32 init GEMM: partial[kz][m][n] = mean[m] . [Wh;Wc][n] over K-slice
__global__ __launch_bounds__(256) void initk(
    const float* __restrict__ mean,
    const float* __restrict__ Wh, const float* __restrict__ Wc,
    float* __restrict__ partial)
{
    __shared__ float As[64][33];
    __shared__ float Bs2[64][33];
    const int n0 = blockIdx.x * 64;    // 0..960 (1024 = Wh|Wc stacked)
    const int m0 = blockIdx.y * 64;    // 0,64
    const int kz = blockIdx.z;         // 0..7
    const int tid = threadIdx.x;
    const int tx = tid & 15, ty = tid >> 4;
    float acc[4][4] = {};

    for (int k0 = kz * 256; k0 < kz * 256 + 256; k0 += 32) {
#pragma unroll
        for (int i = 0; i < 2; ++i) {
            int e  = tid + i * 256;
            int r  = e >> 3;
            int cc = (e & 7) << 2;
            float4 va = *reinterpret_cast<const float4*>(
                mean + (size_t)(m0 + r) * Fz + k0 + cc);
            As[r][cc + 0] = va.x; As[r][cc + 1] = va.y;
            As[r][cc + 2] = va.z; As[r][cc + 3] = va.w;
            int n = n0 + r;
            const float* Brow = (n < Hz) ? (Wh + (size_t)n * Fz)
                                         : (Wc + (size_t)(n - Hz) * Fz);
            float4 vb = *reinterpret_cast<const float4*>(Brow + k0 + cc);
            Bs2[r][cc + 0] = vb.x; Bs2[r][cc + 1] = vb.y;
            Bs2[r][cc + 2] = vb.z; Bs2[r][cc + 3] = vb.w;
        }
        __syncthreads();
#pragma unroll
        for (int kk = 0; kk < 32; ++kk) {
            float a[4], bb[4];
#pragma unroll
            for (int i = 0; i < 4; ++i) a[i] = As[ty * 4 + i][kk];
#pragma unroll
            for (int j = 0; j < 4; ++j) bb[j] = Bs2[tx * 4 + j][kk];
#pragma unroll
            for (int i = 0; i < 4; ++i)
#pragma unroll
                for (int j = 0; j < 4; ++j)
                    acc[i][j] += a[i] * bb[j];
        }
        __syncthreads();
    }
#pragma unroll
    for (int i = 0; i < 4; ++i)
#pragma unroll
        for (int j = 0; j < 4; ++j)
            partial[((size_t)kz * 128 + m0 + ty * 4 + i) * 1024 + n0 + tx * 4 + j]
                = acc[i][j];
}

// ---------------------------------------------------------------------------
// reduce split-K partials; n<512 -> h0 (bf16 hi/lo), n>=512 -> c0 fp32
__global__ __launch_bounds__(256) void init_reduce(
    const float* __restrict__ partial,
    const float* __restrict__ bh, const float* __restrict__ bc,
    ushort* __restrict__ haHi, ushort* __restrict__ haLo,
    float* __restrict__ c0f)
{
    int idx = blockIdx.x * 256 + threadIdx.x;
    if (idx >= 128 * 1024) return;
    int m = idx >> 10, n = idx & 1023;
    float s = 0.f;
#pragma unroll
    for (int z = 0; z < 8; ++z)
        s += partial[((size_t)z * 128 + m) * 1024 + n];
    if (n < Hz) {
        s += bh[n];
        ushort hh = f2b(s);
        haHi[(size_t)m * Hz + n] = hh;
        haLo[(size_t)m * Hz + n] = f2b(s - b2f(hh));
    } else {
        c0f[(size_t)m * Hz + (n - Hz)] = s + bc[n - Hz];
    }
}

// ---------------------------------------------------------------------------
// bf16 MFMA GEMM, 2-phase double-buffered staging (T3-minimum) + XCD swizzle
__global__ __launch_bounds__(256) void gemm_mfma(
    const ushort* __restrict__ A,
    const ushort* __restrict__ B,
    const float* __restrict__ bias,
    float* __restrict__ C,
    int Nb, int ldc, int K)
{
    __shared__ short Al[2][128 * 32];
    __shared__ short Bl[2][128 * 32];
    const int tid  = threadIdx.x;
    const int w    = tid >> 6;
    const int lane = tid & 63;

    // bijective XCD swizzle: contiguous grid chunk per XCD
    const int nwg  = gridDim.x * gridDim.y;
    int orig = blockIdx.y * gridDim.x + blockIdx.x;
    int q = nwg >> 3, r = nwg & 7;
    int xcd = orig & 7, local = orig >> 3;
    int wgid = (xcd < r ? xcd * (q + 1) : r * (q + 1) + (xcd - r) * q) + local;
    const int m0 = (wgid / gridDim.x) * 128;
    const int n0 = (wgid % gridDim.x) * 128;
    const int wr = w >> 1, wc = w & 1;

    f32x4 acc[4][4] = {};

    const int srow = w * 32 + (lane >> 2);
    const int scol = (lane & 3) * 16;
    const char* Ag = (const char*)(A + (size_t)(m0 + srow) * K) + scol;
    const char* Bg = (const char*)(B + (size_t)(n0 + srow) * K) + scol;
    const size_t rstep = (size_t)16 * K * 2;
    const int ldsb = (w * 32) * 32;           // wave-uniform LDS row base

    const int ko = (lane >> 4) * 8;
    const int fr = lane & 15;
    const int nk = K >> 5;

    // prologue: stage tile 0 into buf 0
    {
        gload_lds16(Ag,         Al[0] + ldsb);
        gload_lds16(Ag + rstep, Al[0] + ldsb + 16 * 32);
        gload_lds16(Bg,         Bl[0] + ldsb);
        gload_lds16(Bg + rstep, Bl[0] + ldsb + 16 * 32);
    }
    __syncthreads();

    int cur = 0;
    for (int k = 0; k < nk; ++k) {
        if (k + 1 < nk) {
            const size_t kb = (size_t)(k + 1) * 64;   // 32 elems * 2B
            gload_lds16(Ag + kb,         Al[cur ^ 1] + ldsb);
            gload_lds16(Ag + kb + rstep, Al[cur ^ 1] + ldsb + 16 * 32);
            gload_lds16(Bg + kb,         Bl[cur ^ 1] + ldsb);
            gload_lds16(Bg + kb + rstep, Bl[cur ^ 1] + ldsb + 16 * 32);
        }
        bf16x8 af[4], bf[4];
#pragma unroll
        for (int i = 0; i < 4; ++i)
            af[i] = *reinterpret_cast<const bf16x8*>(&Al[cur][(wr * 64 + i * 16 + fr) * 32 + ko]);
#pragma unroll
        for (int j = 0; j < 4; ++j)
            bf[j] = *reinterpret_cast<const bf16x8*>(&Bl[cur][(wc * 64 + j * 16 + fr) * 32 + ko]);
#pragma unroll
        for (int i = 0; i < 4; ++i)
#pragma unroll
            for (int j = 0; j < 4; ++j)
                acc[i][j] = __builtin_amdgcn_mfma_f32_16x16x32_bf16(
                    af[i], bf[j], acc[i][j], 0, 0, 0);
        __syncthreads();   // drains staged loads (vmcnt) + read completion
        cur ^= 1;
    }

    const int r0 = (lane >> 4) * 4;
#pragma unroll
    for (int i = 0; i < 4; ++i) {
        int row = m0 + wr * 64 + i * 16 + r0;
#pragma unroll
        for (int j = 0; j < 4; ++j) {
            int col = n0 + wc * 64 + j * 16 + fr;
            if (col < Nb) {
                float bb = bias ? bias[col] : 0.f;
#pragma unroll
                for (int rr = 0; rr < 4; ++rr)
                    C[(size_t)(row + rr) * ldc + col] = acc[i][j][rr] + bb;
            }
        }
    }
}

// ---------------------------------------------------------------------------
// One LSTM step, direct-to-VGPR MFMA. Grid (128 col-groups, 4 m-quarters),
// 64 thr = 1 wave -> 512 blocks, 2 per CU.
__global__ __launch_bounds__(64) void lstm_step2(
    const float* __restrict__ xg,
    const ushort* __restrict__ Whi,
    const ushort* __restrict__ Ah,  const ushort* __restrict__ Alo,
    ushort* __restrict__ Oh, ushort* __restrict__ Ol,
    float* __restrict__ cst, ushort* __restrict__ hsb, int t)
{
    __shared__ float Cl[32][17];

    const int tid  = threadIdx.x;
    const int lane = tid & 63;
    const int fr   = lane & 15;
    const int hi4  = lane >> 4;           // 0..3
    const int n0   = blockIdx.x * 16;
    const int j0   = n0 >> 2;             // 4 h-indices per block
    const int m0w  = blockIdx.y * 32;     // m quarter

    f32x4 acc[2] = {};

    const ushort* Bp  = Whi + (size_t)(n0 + fr) * Hz;
    const ushort* Ap0 = Ah  + (size_t)(m0w + fr) * Hz;
    const ushort* Ap1 = Ah  + (size_t)(m0w + 16 + fr) * Hz;
    const ushort* Lp0 = Alo + (size_t)(m0w + fr) * Hz;
    const ushort* Lp1 = Alo + (size_t)(m0w + 16 + fr) * Hz;

#pragma unroll
    for (int kc = 0; kc < 16; ++kc) {
        const size_t koff = (size_t)kc * 32 + hi4 * 8;
        bf16x8 bv  = *reinterpret_cast<const bf16x8*>(Bp  + koff);
        bf16x8 ah0 = *reinterpret_cast<const bf16x8*>(Ap0 + koff);
        bf16x8 ah1 = *reinterpret_cast<const bf16x8*>(Ap1 + koff);
        bf16x8 al0 = *reinterpret_cast<const bf16x8*>(Lp0 + koff);
        bf16x8 al1 = *reinterpret_cast<const bf16x8*>(Lp1 + koff);
        acc[0] = __builtin_amdgcn_mfma_f32_16x16x32_bf16(ah0, bv, acc[0], 0, 0, 0);
        acc[1] = __builtin_amdgcn_mfma_f32_16x16x32_bf16(ah1, bv, acc[1], 0, 0, 0);
        acc[0] = __builtin_amdgcn_mfma_f32_16x16x32_bf16(al0, bv, acc[0], 0, 0, 0);
        acc[1] = __builtin_amdgcn_mfma_f32_16x16x32_bf16(al1, bv, acc[1], 0, 0, 0);
    }

    // regroup gates into Cl[local m][col]; C/D layout: col=fr, row=hi4*4+r
#pragma unroll
    for (int i = 0; i < 2; ++i)
#pragma unroll
        for (int r = 0; r < 4; ++r)
            Cl[i * 16 + hi4 * 4 + r][fr] = acc[i][r];
    __syncthreads();

    // elementwise: 64 threads, each owns (local m = tid>>1, 2 h-indices)
    {
        const int lm = tid >> 1;
        const int m  = m0w + lm;
        const int hp = (tid & 1) * 2;
        const float* xr = xg + ((size_t)m * TM + t) * G4 + n0 + 4 * hp;
        float4 x0 = *reinterpret_cast<const float4*>(xr);
        float4 x1 = *reinterpret_cast<const float4*>(xr + 4);
        float2 cc = *reinterpret_cast<const float2*>(cst + (size_t)m * Hz + j0 + hp);

        float gi0 = Cl[lm][4 * hp + 0] + x0.x;
        float gf0 = Cl[lm][4 * hp + 1] + x0.y;
        float gg0 = Cl[lm][4 * hp + 2] + x0.z;
        float go0 = Cl[lm][4 * hp + 3] + x0.w;
        float gi1 = Cl[lm][4 * hp + 4] + x1.x;
        float gf1 = Cl[lm][4 * hp + 5] + x1.y;
        float gg1 = Cl[lm][4 * hp + 6] + x1.z;
        float go1 = Cl[lm][4 * hp + 7] + x1.w;

        float i0 = 1.f / (1.f + expf(-gi0));
        float f0 = 1.f / (1.f + expf(-gf0));
        float g0 = tanhf(gg0);
        float o0 = 1.f / (1.f + expf(-go0));
        float i1 = 1.f / (1.f + expf(-gi1));
        float f1 = 1.f / (1.f + expf(-gf1));
        float g1 = tanhf(gg1);
        float o1 = 1.f / (1.f + expf(-go1));

        float cn0 = f0 * cc.x + i0 * g0;
        float cn1 = f1 * cc.y + i1 * g1;
        float h0v = o0 * tanhf(cn0);
        float h1v = o1 * tanhf(cn1);

        float2 cno = {cn0, cn1};
        *reinterpret_cast<float2*>(cst + (size_t)m * Hz + j0 + hp) = cno;

        ushort hh0 = f2b(h0v), hh1 = f2b(h1v);
        ushort hl0 = f2b(h0v - b2f(hh0)), hl1 = f2b(h1v - b2f(hh1));
        uint uh = (uint)hh0 | ((uint)hh1 << 16);
        uint ul = (uint)hl0 | ((uint)hl1 << 16);
        *reinterpret_cast<uint*>(Oh + (size_t)m * Hz + j0 + hp) = uh;
        *reinterpret_cast<uint*>(Ol + (size_t)m * Hz + j0 + hp) = ul;
        *reinterpret_cast<uint*>(hsb + ((size_t)m * TM + t) * Hz + j0 + hp) = uh;
    }
}

// ---------------------------------------------------------------------------
extern "C" void kernel_launch(void* const* d_in, const int* in_sizes, int n_in,
                              void* d_out, int out_size, void* d_ws, size_t ws_size,
                              hipStream_t stream) {
    const float* features = (const float*)d_in[0];
    const int*   captions = (const int*)d_in[1];
    const float* emb_W    = (const float*)d_in[2];
    const float* W_ih     = (const float*)d_in[3];
    const float* W_hh     = (const float*)d_in[4];
    const float* b_ih     = (const float*)d_in[5];
    const float* b_hh     = (const float*)d_in[6];
    const float* Wh       = (const float*)d_in[7];
    const float* bh       = (const float*)d_in[8];
    const float* Wc       = (const float*)d_in[9];
    const float* bc       = (const float*)d_in[10];
    const float* fc_W     = (const float*)d_in[11];
    const float* fc_b     = (const float*)d_in[12];
    float* out = (float*)d_out;

    // workspace carve-up
    float* w    = (float*)d_ws;
    float* mean = w;                            // 262144 f
    float* xg   = mean + Bz * Fz;               // 8,126,464 f (partial overlaid)
    float* partial = xg;                        // [8][128][1024] f, used pre-xg
    float* c0f  = xg + (size_t)Mrows * G4;      // 65536 f
    float* bP   = c0f + Bz * Hz;                // 2048 f
    ushort* embg = (ushort*)(bP + G4);          // 3968*512
    ushort* WihP = embg + (size_t)Mrows * Ez;   // 2048*512
    ushort* Whi  = WihP + (size_t)G4 * Ez;      // 2048*512
    ushort* fcWb = Whi + (size_t)G4 * Hz;       // 10112*512
    ushort* hsb  = fcWb + (size_t)NPAD * Hz;    // 3968*512
    ushort* haHi = hsb + (size_t)Mrows * Hz;    // 128*512 each below
    ushort* haLo = haHi + Bz * Hz;
    ushort* hbHi = haLo + Bz * Hz;
    ushort* hbLo = hbHi + Bz * Hz;

    meanpool<<<(Bz * Fz / 4) / 256, 256, 0, stream>>>(features, mean);
    gather_cvt_emb<<<(Mrows * (Ez / 4) + 255) / 256, 256, 0, stream>>>(emb_W, captions, embg);
    permute_wih<<<(G4 * (Ez / 4)) / 256, 256, 0, stream>>>(W_ih, b_ih, b_hh, WihP, bP);
    permute_whh<<<(G4 * (Hz / 4)) / 256, 256, 0, stream>>>(W_hh, Whi);
    cvt_bf16_pad4<<<(NPAD * Hz / 4 + 255) / 256, 256, 0, stream>>>(
        fc_W, fcWb, Vz * Hz / 4, NPAD * Hz / 4);

    // init h0/c0: split-K fp32 into partial (overlaid on xg), then reduce
    initk<<<dim3(16, 2, 8), 256, 0, stream>>>(mean, Wh, Wc, partial);
    init_reduce<<<(128 * 1024) / 256, 256, 0, stream>>>(
        partial, bh, bc, haHi, haLo, c0f);

    // x-side gates (overwrites partial region — after init_reduce)
    gemm_mfma<<<dim3(G4 / 128, Mrows / 128), 256, 0, stream>>>(
        embg, WihP, bP, xg, G4, G4, Ez);

    // recurrence: 31 per-step launches, 512 single-wave blocks each
    for (int t = 0; t < TM; ++t) {
        const ushort* ih = (t & 1) ? hbHi : haHi;
        const ushort* il = (t & 1) ? hbLo : haLo;
        ushort* oh = (t & 1) ? haHi : hbHi;
        ushort* ol = (t & 1) ? haLo : hbLo;
        lstm_step2<<<dim3(G4 / 16, 4), 64, 0, stream>>>(
            xg, Whi, ih, il, oh, ol, c0f, hsb, t);
    }

    // output projection
    gemm_mfma<<<dim3(NPAD / 128, Mrows / 128), 256, 0, stream>>>(
        hsb, fcWb, fc_b, out, Vz, Vz, Hz);
}